// Round 7
// baseline (178.198 us; speedup 1.0000x reference)
//
#include <hip/hip_runtime.h>
#include <hip/hip_bf16.h>

typedef unsigned short u16;
typedef unsigned int   u32;
typedef __attribute__((ext_vector_type(8))) short short8;
typedef __attribute__((ext_vector_type(4))) float f32x4;

static __device__ __forceinline__ u16 f2b(float f) {
    __hip_bfloat16 h = __float2bfloat16(f);
    return *reinterpret_cast<u16*>(&h);
}
static __device__ __forceinline__ u32 pk2(float a, float b) {
    return (u32)f2b(a) | ((u32)f2b(b) << 16);
}

#define LDK 72  // GEMM LDS row stride (bf16): 144B rows, 16B-aligned, 2-way-max bank aliasing (free)

// ---------------- Kernel 0: AB = lambda * A, bf16.  1,048,576 elems / 8 per thread / 256 = 512 blocks ----------------
__global__ __launch_bounds__(256) void prep_A(const float* __restrict__ A,
                                              const float* __restrict__ LAM,
                                              u16* __restrict__ AB) {
    const float lam = LAM[0];
    const int i = (blockIdx.x * 256 + threadIdx.x) * 8;
    const float4 a = *(const float4*)(A + i);
    const float4 b = *(const float4*)(A + i + 4);
    uint4 o;
    o.x = pk2(lam * a.x, lam * a.y);
    o.y = pk2(lam * a.z, lam * a.w);
    o.z = pk2(lam * b.x, lam * b.y);
    o.w = pk2(lam * b.z, lam * b.w);
    *(uint4*)(AB + i) = o;
}

// ---------------- Kernel 1: QKV projection ----------------
__global__ __launch_bounds__(256) void qkv_gemm(const float* __restrict__ X,
                                                const float* __restrict__ W,
                                                u16* __restrict__ qo,
                                                u16* __restrict__ ko,
                                                u16* __restrict__ vt) {
    __shared__ u16 SH[2 * 128 * LDK];   // Xs | Ws; reused as transpose buf in v-epilogue
    u16* Xs = SH;
    u16* Ws = SH + 128 * LDK;
    const int t    = threadIdx.x;
    const int m0   = blockIdx.x << 7;
    const int o0   = blockIdx.y << 7;
    const int lane = t & 63;
    const int wid  = t >> 6;
    const int wr   = (wid >> 1) << 6;
    const int wc   = (wid & 1) << 6;
    const int ln   = lane & 15;
    const int quad = lane >> 4;

    const int r  = t >> 1;
    const int hf = (t & 1) << 5;
    const float* xg = X + (size_t)(m0 + r) * 256 + hf;
    const float* wg = W + (size_t)(o0 + r) * 256 + hf;
    uint4* xls = (uint4*)&Xs[r * LDK + hf];
    uint4* wls = (uint4*)&Ws[r * LDK + hf];

    f32x4 acc[4][4] = {};

    for (int kc = 0; kc < 256; kc += 64) {
        const float4* xp = (const float4*)(xg + kc);
        const float4* wp = (const float4*)(wg + kc);
        float xv[32], wv[32];
#pragma unroll
        for (int i = 0; i < 8; ++i) {
            float4 a = xp[i]; xv[4*i] = a.x; xv[4*i+1] = a.y; xv[4*i+2] = a.z; xv[4*i+3] = a.w;
            float4 b = wp[i]; wv[4*i] = b.x; wv[4*i+1] = b.y; wv[4*i+2] = b.z; wv[4*i+3] = b.w;
        }
        uint4 xq[4], wq[4];
#pragma unroll
        for (int i = 0; i < 4; ++i) {
            xq[i].x = pk2(xv[8*i],   xv[8*i+1]); xq[i].y = pk2(xv[8*i+2], xv[8*i+3]);
            xq[i].z = pk2(xv[8*i+4], xv[8*i+5]); xq[i].w = pk2(xv[8*i+6], xv[8*i+7]);
            wq[i].x = pk2(wv[8*i],   wv[8*i+1]); wq[i].y = pk2(wv[8*i+2], wv[8*i+3]);
            wq[i].z = pk2(wv[8*i+4], wv[8*i+5]); wq[i].w = pk2(wv[8*i+6], wv[8*i+7]);
        }
        __syncthreads();
#pragma unroll
        for (int i = 0; i < 4; ++i) { xls[i] = xq[i]; wls[i] = wq[i]; }
        __syncthreads();
#pragma unroll
        for (int kk = 0; kk < 64; kk += 32) {
            short8 a[4], b[4];
#pragma unroll
            for (int i = 0; i < 4; ++i)
                a[i] = *(const short8*)&Xs[(wr + i * 16 + ln) * LDK + kk + quad * 8];
#pragma unroll
            for (int j = 0; j < 4; ++j)
                b[j] = *(const short8*)&Ws[(wc + j * 16 + ln) * LDK + kk + quad * 8];
#pragma unroll
            for (int i = 0; i < 4; ++i)
#pragma unroll
                for (int j = 0; j < 4; ++j)
                    acc[i][j] = __builtin_amdgcn_mfma_f32_16x16x32_bf16(a[i], b[j], acc[i][j], 0, 0, 0);
        }
    }

    const int which = o0 >> 8;  // 0=q, 1=k, 2=v
    if (which < 2) {
        const float qscale = (which == 0) ? 0.17677669529663689f : 1.0f;  // 32^-0.5 folded into q
        u16* dst = (which == 0) ? qo : ko;
#pragma unroll
        for (int i = 0; i < 4; ++i) {
            const int mb = m0 + wr + i * 16 + quad * 4;  // C/D: row = quad*4 + reg
#pragma unroll
            for (int j = 0; j < 4; ++j) {
                const int o   = o0 + wc + j * 16 + ln;   // C/D: col = lane&15
                const int rem = o & 255;
                const int hh  = rem >> 5;
                const int dd  = rem & 31;
#pragma unroll
                for (int rr = 0; rr < 4; ++rr) {
                    const int m  = mb + rr;
                    const int bt = m >> 9;
                    const int n  = m & 511;
                    dst[(((size_t)bt * 8 + hh) * 512 + n) * 32 + dd] = f2b(acc[i][j][rr] * qscale);
                }
            }
        }
    } else {
        // v: transpose 128m x 128o tile via LDS, packed 16B stores to vt[bh][dd][n]
        __syncthreads();
        u16* T = SH;                           // 128 rows (o_local) x stride 136 (m_local)
#pragma unroll
        for (int i = 0; i < 4; ++i) {
            const int ml = wr + i * 16 + quad * 4;
#pragma unroll
            for (int j = 0; j < 4; ++j) {
                const int ol = wc + j * 16 + ln;
                uint2 pv;
                pv.x = pk2(acc[i][j][0], acc[i][j][1]);
                pv.y = pk2(acc[i][j][2], acc[i][j][3]);
                *(uint2*)&T[ol * 136 + ml] = pv;
            }
        }
        __syncthreads();
        const int row = t >> 1;
        const int seg = (t & 1) << 6;
        const int o   = o0 + row;
        const int rem = o & 255;
        const int hh  = rem >> 5;
        const int dd  = rem & 31;
        const int bt  = m0 >> 9;
        u16* dstv = vt + (((size_t)bt * 8 + hh) * 32 + dd) * 512 + (m0 & 511) + seg;
#pragma unroll
        for (int kk2 = 0; kk2 < 8; ++kk2) {
            uint4 val = *(const uint4*)&T[row * 136 + seg + kk2 * 8];
            *(uint4*)(dstv + kk2 * 8) = val;
        }
    }
}

// ---------------- Kernel 2: MFMA flash attention — barrier-free, register-pipelined ----------------
// Per jt: VT frags load at iter top (used ~700cyc later in PV); S-phase runs entirely from
// registers (K frags + bf16 lambda*A C-operands preloaded previous iter); K/A for jt+1 refill
// during PV+shuffles. No __syncthreads anywhere in the loop; single-pass softmax (scores bounded).
__global__ __launch_bounds__(256, 3) void attn_mfma(const u16* __restrict__ Q,
                                                    const u16* __restrict__ K,
                                                    const u16* __restrict__ VT,
                                                    const u16* __restrict__ AB,
                                                    const int* __restrict__ NF,
                                                    u16* __restrict__ AO) {
    __shared__ u16 Ps[4][32 * 136];   // per-wave P^T [q][key], stride 136
    const int t    = threadIdx.x;
    const int w    = t >> 6;
    const int lane = t & 63;
    const int ln   = lane & 15;
    const int quad = lane >> 4;
    // XCD swizzle: blocks sharing an A-tile keep blockIdx%8 invariant
    const int L    = blockIdx.x;
    const int g    = (L & 7) + (((L >> 3) & 1) << 3);  // 0..15
    const int j    = L >> 4;                           // 0..63
    const int qt   = g & 3;
    const int h    = j & 7;
    const int bt   = (g >> 2) * 8 + (j >> 3);
    const int bh   = bt * 8 + h;
    const int q0   = qt * 128 + w * 32;
    const size_t base = (size_t)bh * (512 * 32);
    const int b    = bt / NF[0];
    const u16* Ab   = AB + (size_t)b * 512 * 512;
    const u16* Ar0  = Ab + (size_t)(q0 + ln) * 512 + quad * 4;
    const u16* Ar1  = Ab + (size_t)(q0 + 16 + ln) * 512 + quad * 4;

    short8 qf[2];
#pragma unroll
    for (int nt = 0; nt < 2; ++nt)
        qf[nt] = *(const short8*)(Q + base + (size_t)(q0 + nt * 16 + ln) * 32 + quad * 8);

    // ---- preload jt=0: K frags + A C-operand frags ----
    short8 kf[8];
    uint2  ar[16];
#pragma unroll
    for (int mt = 0; mt < 8; ++mt) {
        kf[mt]       = *(const short8*)(K + base + (size_t)(mt * 16 + ln) * 32 + quad * 8);
        ar[2*mt]     = *(const uint2*)(Ar0 + mt * 16);
        ar[2*mt + 1] = *(const uint2*)(Ar1 + mt * 16);
    }

    f32x4 o[2][2] = {};            // O[q-tile][dim-tile], C-layout
    float lsum0 = 0.f, lsum1 = 0.f;

    for (int jt = 0; jt < 512; jt += 128) {
        const int jn = (jt + 128) & 511;   // wrapped: last-iter refill valid-but-unused
        // VT frags for this jt: consumed at the bottom (PV) -> full S-phase of slack
        short8 vb[8];
#pragma unroll
        for (int ks = 0; ks < 4; ++ks) {
            vb[2*ks]     = *(const short8*)(VT + base + (size_t)ln * 512        + jt + ks * 32 + quad * 8);
            vb[2*ks + 1] = *(const short8*)(VT + base + (size_t)(16 + ln) * 512 + jt + ks * 32 + quad * 8);
        }

        // ---- S-phase: all operands in registers ----
        float ps0 = 0.f, ps1 = 0.f;
#pragma unroll
        for (int mt = 0; mt < 8; ++mt) {
            f32x4 c0, c1;
            c0[0] = __uint_as_float(ar[2*mt].x << 16);     c0[1] = __uint_as_float(ar[2*mt].x & 0xffff0000u);
            c0[2] = __uint_as_float(ar[2*mt].y << 16);     c0[3] = __uint_as_float(ar[2*mt].y & 0xffff0000u);
            c1[0] = __uint_as_float(ar[2*mt+1].x << 16);   c1[1] = __uint_as_float(ar[2*mt+1].x & 0xffff0000u);
            c1[2] = __uint_as_float(ar[2*mt+1].y << 16);   c1[3] = __uint_as_float(ar[2*mt+1].y & 0xffff0000u);
            const f32x4 s0 = __builtin_amdgcn_mfma_f32_16x16x32_bf16(kf[mt], qf[0], c0, 0, 0, 0);
            const f32x4 s1 = __builtin_amdgcn_mfma_f32_16x16x32_bf16(kf[mt], qf[1], c1, 0, 0, 0);
            const float p00 = __expf(s0[0]), p01 = __expf(s0[1]), p02 = __expf(s0[2]), p03 = __expf(s0[3]);
            const float p10 = __expf(s1[0]), p11 = __expf(s1[1]), p12 = __expf(s1[2]), p13 = __expf(s1[3]);
            ps0 += (p00 + p01) + (p02 + p03);
            ps1 += (p10 + p11) + (p12 + p13);
            uint2 w0; w0.x = pk2(p00, p01); w0.y = pk2(p02, p03);
            uint2 w1; w1.x = pk2(p10, p11); w1.y = pk2(p12, p13);
            *(uint2*)&Ps[w][ln * 136 + mt * 16 + quad * 4]        = w0;
            *(uint2*)&Ps[w][(16 + ln) * 136 + mt * 16 + quad * 4] = w1;
        }

        // ---- refill K + A for next jt (kf/ar dead after S-phase); lands during PV ----
#pragma unroll
        for (int mt = 0; mt < 8; ++mt) {
            kf[mt]       = *(const short8*)(K + base + (size_t)(jn + mt * 16 + ln) * 32 + quad * 8);
            ar[2*mt]     = *(const uint2*)(Ar0 + jn + mt * 16);
            ar[2*mt + 1] = *(const uint2*)(Ar1 + jn + mt * 16);
        }

        ps0 += __shfl_xor(ps0, 16); ps0 += __shfl_xor(ps0, 32); lsum0 += ps0;
        ps1 += __shfl_xor(ps1, 16); ps1 += __shfl_xor(ps1, 32); lsum1 += ps1;

        // ---- PV: O += P.V  (A-frag from own LDS strip, B-frag prefetched) ----
#pragma unroll
        for (int ks = 0; ks < 4; ++ks) {
            short8 pa0 = *(const short8*)&Ps[w][ln * 136 + ks * 32 + quad * 8];
            short8 pa1 = *(const short8*)&Ps[w][(16 + ln) * 136 + ks * 32 + quad * 8];
            o[0][0] = __builtin_amdgcn_mfma_f32_16x16x32_bf16(pa0, vb[2*ks],     o[0][0], 0, 0, 0);
            o[0][1] = __builtin_amdgcn_mfma_f32_16x16x32_bf16(pa0, vb[2*ks + 1], o[0][1], 0, 0, 0);
            o[1][0] = __builtin_amdgcn_mfma_f32_16x16x32_bf16(pa1, vb[2*ks],     o[1][0], 0, 0, 0);
            o[1][1] = __builtin_amdgcn_mfma_f32_16x16x32_bf16(pa1, vb[2*ks + 1], o[1][1], 0, 0, 0);
        }
    }

    // ---- epilogue: O /= l, heads back to [BT,N,D] bf16 ----
#pragma unroll
    for (int r = 0; r < 4; ++r) {
        const int src = quad * 4 + r;
        const float i0 = 1.f / __shfl(lsum0, src);
        const float i1 = 1.f / __shfl(lsum1, src);
        const int n0 = qt * 128 + w * 32 + quad * 4 + r;
#pragma unroll
        for (int ntd = 0; ntd < 2; ++ntd) {
            AO[((size_t)bt * 512 + n0) * 256 + h * 32 + ntd * 16 + ln]      = f2b(o[0][ntd][r] * i0);
            AO[((size_t)bt * 512 + n0 + 16) * 256 + h * 32 + ntd * 16 + ln] = f2b(o[1][ntd][r] * i1);
        }
    }
}

// ---------------- Kernel 3: output projection + bias ----------------
__global__ __launch_bounds__(256) void proj_gemm(const u16* __restrict__ X,
                                                 const float* __restrict__ W,
                                                 const float* __restrict__ BIAS,
                                                 float* __restrict__ OUT) {
    __shared__ u16 Xs[128 * LDK];
    __shared__ u16 Ws[128 * LDK];
    const int t    = threadIdx.x;
    const int m0   = blockIdx.x << 7;
    const int o0   = blockIdx.y << 7;
    const int lane = t & 63;
    const int wid  = t >> 6;
    const int wr   = (wid >> 1) << 6;
    const int wc   = (wid & 1) << 6;
    const int ln   = lane & 15;
    const int quad = lane >> 4;

    const int r  = t >> 1;
    const int hf = (t & 1) << 5;
    const u16*   xg = X + (size_t)(m0 + r) * 256 + hf;
    const float* wg = W + (size_t)(o0 + r) * 256 + hf;
    uint4* xls = (uint4*)&Xs[r * LDK + hf];
    uint4* wls = (uint4*)&Ws[r * LDK + hf];

    f32x4 acc[4][4] = {};

    for (int kc = 0; kc < 256; kc += 64) {
        const uint4*  xp = (const uint4*)(xg + kc);
        const float4* wp = (const float4*)(wg + kc);
        uint4 x0 = xp[0], x1 = xp[1], x2 = xp[2], x3 = xp[3];
        float wv[32];
#pragma unroll
        for (int i = 0; i < 8; ++i) {
            float4 b = wp[i]; wv[4*i] = b.x; wv[4*i+1] = b.y; wv[4*i+2] = b.z; wv[4*i+3] = b.w;
        }
        uint4 wq[4];
#pragma unroll
        for (int i = 0; i < 4; ++i) {
            wq[i].x = pk2(wv[8*i],   wv[8*i+1]); wq[i].y = pk2(wv[8*i+2], wv[8*i+3]);
            wq[i].z = pk2(wv[8*i+4], wv[8*i+5]); wq[i].w = pk2(wv[8*i+6], wv[8*i+7]);
        }
        __syncthreads();
        xls[0] = x0; xls[1] = x1; xls[2] = x2; xls[3] = x3;
#pragma unroll
        for (int i = 0; i < 4; ++i) wls[i] = wq[i];
        __syncthreads();
#pragma unroll
        for (int kk = 0; kk < 64; kk += 32) {
            short8 a[4], b[4];
#pragma unroll
            for (int i = 0; i < 4; ++i)
                a[i] = *(const short8*)&Xs[(wr + i * 16 + ln) * LDK + kk + quad * 8];
#pragma unroll
            for (int j = 0; j < 4; ++j)
                b[j] = *(const short8*)&Ws[(wc + j * 16 + ln) * LDK + kk + quad * 8];
#pragma unroll
            for (int i = 0; i < 4; ++i)
#pragma unroll
                for (int j = 0; j < 4; ++j)
                    acc[i][j] = __builtin_amdgcn_mfma_f32_16x16x32_bf16(a[i], b[j], acc[i][j], 0, 0, 0);
        }
    }

#pragma unroll
    for (int i = 0; i < 4; ++i) {
        const int mb = m0 + wr + i * 16 + quad * 4;
#pragma unroll
        for (int j = 0; j < 4; ++j) {
            const int o  = o0 + wc + j * 16 + ln;
            const float bo = BIAS[o];
#pragma unroll
            for (int rr = 0; rr < 4; ++rr) {
                const int m = mb + rr;
                OUT[(size_t)m * 256 + o] = acc[i][j][rr] + bo;
            }
        }
    }
}

extern "C" void kernel_launch(void* const* d_in, const int* in_sizes, int n_in,
                              void* d_out, int out_size, void* d_ws, size_t ws_size,
                              hipStream_t stream) {
    (void)in_sizes; (void)n_in; (void)out_size; (void)ws_size;
    const float* x     = (const float*)d_in[0];   // [32,512,256] fp32
    const float* A     = (const float*)d_in[1];   // [4,512,512]  fp32
    const float* Wqkv  = (const float*)d_in[2];   // [768,256]    fp32
    const float* Wproj = (const float*)d_in[3];   // [256,256]    fp32
    const float* bproj = (const float*)d_in[4];   // [256]        fp32
    const float* lam   = (const float*)d_in[5];   // [1]          fp32
    const int*   nf    = (const int*)d_in[6];     // [1]          int32
    float* out = (float*)d_out;                   // [32,512,256] fp32

    // ws: q,k [bh,n,hd] + vt [bh,hd,n] bf16 (8MB each) + ao (8MB) + AB lambda*A bf16 (2MB) = 34MB
    u16* q  = (u16*)d_ws;
    u16* k  = q + 4194304;
    u16* vt = k + 4194304;
    u16* ao = vt + 4194304;
    u16* AB = ao + 4194304;

    prep_A  <<<dim3(512), 256, 0, stream>>>(A, lam, AB);
    qkv_gemm<<<dim3(128, 6), 256, 0, stream>>>(x, Wqkv, q, k, vt);
    attn_mfma<<<dim3(1024), 256, 0, stream>>>(q, k, vt, AB, nf, ao);
    proj_gemm<<<dim3(128, 2), 256, 0, stream>>>(ao, Wproj, bproj, out);
}

// Round 8
// 168.127 us; speedup vs baseline: 1.0599x; 1.0599x over previous
//
#include <hip/hip_runtime.h>
#include <hip/hip_bf16.h>

typedef unsigned short u16;
typedef unsigned int   u32;
typedef __attribute__((ext_vector_type(8))) short short8;
typedef __attribute__((ext_vector_type(4))) float f32x4;

static __device__ __forceinline__ u16 f2b(float f) {
    __hip_bfloat16 h = __float2bfloat16(f);
    return *reinterpret_cast<u16*>(&h);
}
static __device__ __forceinline__ u32 pk2(float a, float b) {
    return (u32)f2b(a) | ((u32)f2b(b) << 16);
}

#define LDK 72  // GEMM LDS row stride (bf16): 144B rows, 16B-aligned, 2-way-max bank aliasing (free)

// ---------------- Kernel 0: AB = lambda * A, bf16.  1,048,576 / 8 / 256 = 512 blocks ----------------
__global__ __launch_bounds__(256) void prep_A(const float* __restrict__ A,
                                              const float* __restrict__ LAM,
                                              u16* __restrict__ AB) {
    const float lam = LAM[0];
    const int i = (blockIdx.x * 256 + threadIdx.x) * 8;
    const float4 a = *(const float4*)(A + i);
    const float4 b = *(const float4*)(A + i + 4);
    uint4 o;
    o.x = pk2(lam * a.x, lam * a.y);
    o.y = pk2(lam * a.z, lam * a.w);
    o.z = pk2(lam * b.x, lam * b.y);
    o.w = pk2(lam * b.z, lam * b.w);
    *(uint4*)(AB + i) = o;
}

// ---------------- Kernel 1: QKV projection ----------------
__global__ __launch_bounds__(256) void qkv_gemm(const float* __restrict__ X,
                                                const float* __restrict__ W,
                                                u16* __restrict__ qo,
                                                u16* __restrict__ ko,
                                                u16* __restrict__ vt) {
    __shared__ u16 SH[2 * 128 * LDK];   // Xs | Ws; reused as transpose buf in v-epilogue
    u16* Xs = SH;
    u16* Ws = SH + 128 * LDK;
    const int t    = threadIdx.x;
    const int m0   = blockIdx.x << 7;
    const int o0   = blockIdx.y << 7;
    const int lane = t & 63;
    const int wid  = t >> 6;
    const int wr   = (wid >> 1) << 6;
    const int wc   = (wid & 1) << 6;
    const int ln   = lane & 15;
    const int quad = lane >> 4;

    const int r  = t >> 1;
    const int hf = (t & 1) << 5;
    const float* xg = X + (size_t)(m0 + r) * 256 + hf;
    const float* wg = W + (size_t)(o0 + r) * 256 + hf;
    uint4* xls = (uint4*)&Xs[r * LDK + hf];
    uint4* wls = (uint4*)&Ws[r * LDK + hf];

    f32x4 acc[4][4] = {};

    for (int kc = 0; kc < 256; kc += 64) {
        const float4* xp = (const float4*)(xg + kc);
        const float4* wp = (const float4*)(wg + kc);
        float xv[32], wv[32];
#pragma unroll
        for (int i = 0; i < 8; ++i) {
            float4 a = xp[i]; xv[4*i] = a.x; xv[4*i+1] = a.y; xv[4*i+2] = a.z; xv[4*i+3] = a.w;
            float4 b = wp[i]; wv[4*i] = b.x; wv[4*i+1] = b.y; wv[4*i+2] = b.z; wv[4*i+3] = b.w;
        }
        uint4 xq[4], wq[4];
#pragma unroll
        for (int i = 0; i < 4; ++i) {
            xq[i].x = pk2(xv[8*i],   xv[8*i+1]); xq[i].y = pk2(xv[8*i+2], xv[8*i+3]);
            xq[i].z = pk2(xv[8*i+4], xv[8*i+5]); xq[i].w = pk2(xv[8*i+6], xv[8*i+7]);
            wq[i].x = pk2(wv[8*i],   wv[8*i+1]); wq[i].y = pk2(wv[8*i+2], wv[8*i+3]);
            wq[i].z = pk2(wv[8*i+4], wv[8*i+5]); wq[i].w = pk2(wv[8*i+6], wv[8*i+7]);
        }
        __syncthreads();
#pragma unroll
        for (int i = 0; i < 4; ++i) { xls[i] = xq[i]; wls[i] = wq[i]; }
        __syncthreads();
#pragma unroll
        for (int kk = 0; kk < 64; kk += 32) {
            short8 a[4], b[4];
#pragma unroll
            for (int i = 0; i < 4; ++i)
                a[i] = *(const short8*)&Xs[(wr + i * 16 + ln) * LDK + kk + quad * 8];
#pragma unroll
            for (int j = 0; j < 4; ++j)
                b[j] = *(const short8*)&Ws[(wc + j * 16 + ln) * LDK + kk + quad * 8];
#pragma unroll
            for (int i = 0; i < 4; ++i)
#pragma unroll
                for (int j = 0; j < 4; ++j)
                    acc[i][j] = __builtin_amdgcn_mfma_f32_16x16x32_bf16(a[i], b[j], acc[i][j], 0, 0, 0);
        }
    }

    const int which = o0 >> 8;  // 0=q, 1=k, 2=v
    if (which < 2) {
        const float qscale = (which == 0) ? 0.17677669529663689f : 1.0f;  // 32^-0.5 folded into q
        u16* dst = (which == 0) ? qo : ko;
#pragma unroll
        for (int i = 0; i < 4; ++i) {
            const int mb = m0 + wr + i * 16 + quad * 4;  // C/D: row = quad*4 + reg
#pragma unroll
            for (int j = 0; j < 4; ++j) {
                const int o   = o0 + wc + j * 16 + ln;   // C/D: col = lane&15
                const int rem = o & 255;
                const int hh  = rem >> 5;
                const int dd  = rem & 31;
#pragma unroll
                for (int rr = 0; rr < 4; ++rr) {
                    const int m  = mb + rr;
                    const int bt = m >> 9;
                    const int n  = m & 511;
                    dst[(((size_t)bt * 8 + hh) * 512 + n) * 32 + dd] = f2b(acc[i][j][rr] * qscale);
                }
            }
        }
    } else {
        // v: transpose 128m x 128o tile via LDS, packed 16B stores to vt[bh][dd][n]
        __syncthreads();
        u16* T = SH;                           // 128 rows (o_local) x stride 136 (m_local)
#pragma unroll
        for (int i = 0; i < 4; ++i) {
            const int ml = wr + i * 16 + quad * 4;
#pragma unroll
            for (int j = 0; j < 4; ++j) {
                const int ol = wc + j * 16 + ln;
                uint2 pv;
                pv.x = pk2(acc[i][j][0], acc[i][j][1]);
                pv.y = pk2(acc[i][j][2], acc[i][j][3]);
                *(uint2*)&T[ol * 136 + ml] = pv;
            }
        }
        __syncthreads();
        const int row = t >> 1;
        const int seg = (t & 1) << 6;
        const int o   = o0 + row;
        const int rem = o & 255;
        const int hh  = rem >> 5;
        const int dd  = rem & 31;
        const int bt  = m0 >> 9;
        u16* dstv = vt + (((size_t)bt * 8 + hh) * 32 + dd) * 512 + (m0 & 511) + seg;
#pragma unroll
        for (int kk2 = 0; kk2 < 8; ++kk2) {
            uint4 val = *(const uint4*)&T[row * 136 + seg + kk2 * 8];
            *(uint4*)(dstv + kk2 * 8) = val;
        }
    }
}

// ---------------- Kernel 2: MFMA flash attention — cooperative LDS double-buffer ----------------
// K-tile + VT-tile staged ONCE per block per jt (coalesced, shared by 4 waves, dbuf, one barrier).
// Staging loads feed LDS writes before the barrier -> compiler cannot sink them into compute.
// S->exp->PV runs per 32-key chunk from LDS; A (lambda-prescaled bf16) is the MFMA C-operand.
__global__ __launch_bounds__(256, 3) void attn_mfma(const u16* __restrict__ Q,
                                                    const u16* __restrict__ K,
                                                    const u16* __restrict__ VT,
                                                    const u16* __restrict__ AB,
                                                    const int* __restrict__ NF,
                                                    u16* __restrict__ AO) {
    __shared__ u16 Ks[2][128 * 40];   // [buf][key][dim]  80B rows
    __shared__ u16 Vs[2][32 * 136];   // [buf][dim][key]  272B rows
    __shared__ u16 Ps[4][32 * 40];    // per-wave P^T chunk [q][32 keys]
    const int t    = threadIdx.x;
    const int w    = t >> 6;
    const int lane = t & 63;
    const int ln   = lane & 15;
    const int quad = lane >> 4;
    // XCD swizzle: blocks sharing an A-tile keep blockIdx%8 invariant
    const int L    = blockIdx.x;
    const int g    = (L & 7) + (((L >> 3) & 1) << 3);  // 0..15
    const int j    = L >> 4;                           // 0..63
    const int qt   = g & 3;
    const int h    = j & 7;
    const int bt   = (g >> 2) * 8 + (j >> 3);
    const int bh   = bt * 8 + h;
    const int q0   = qt * 128 + w * 32;
    const size_t base = (size_t)bh * (512 * 32);
    const int b    = bt / NF[0];
    const u16* Ab  = AB + (size_t)b * 512 * 512;
    const u16* Ar0 = Ab + (size_t)(q0 + ln) * 512 + quad * 4;
    const u16* Ar1 = Ab + (size_t)(q0 + 16 + ln) * 512 + quad * 4;

    // cooperative staging map (4096 bf16 per tile, 256 threads, 2x uint4 each)
    const int krow = t >> 2, kcol = (t & 3) * 8;   // K rows krow / krow+64
    const int vd   = t >> 4, vn   = (t & 15) * 8;  // VT dims vd / vd+16
    const u16* Kg = K + base;
    const u16* Vg = VT + base;

    // ---- prologue: stage jt=0 ----
    {
        uint4 s0 = *(const uint4*)(Kg + (size_t)krow * 32 + kcol);
        uint4 s1 = *(const uint4*)(Kg + (size_t)(64 + krow) * 32 + kcol);
        uint4 s2 = *(const uint4*)(Vg + (size_t)vd * 512 + vn);
        uint4 s3 = *(const uint4*)(Vg + (size_t)(16 + vd) * 512 + vn);
        *(uint4*)&Ks[0][krow * 40 + kcol]        = s0;
        *(uint4*)&Ks[0][(64 + krow) * 40 + kcol] = s1;
        *(uint4*)&Vs[0][vd * 136 + vn]           = s2;
        *(uint4*)&Vs[0][(16 + vd) * 136 + vn]    = s3;
    }

    short8 qf[2];
#pragma unroll
    for (int nt = 0; nt < 2; ++nt)
        qf[nt] = *(const short8*)(Q + base + (size_t)(q0 + nt * 16 + ln) * 32 + quad * 8);

    f32x4 o[2][2] = {};            // O[q-tile][dim-tile], C-layout
    float lsum0 = 0.f, lsum1 = 0.f;
    __syncthreads();

    int cur = 0;
    for (int jt = 0; jt < 512; jt += 128) {
        const int nxt = cur ^ 1;
        const bool more = jt < 384;
        // ---- stage next tile into regs (consumed after compute -> full phase of slack) ----
        uint4 t0 = {}, t1 = {}, t2 = {}, t3 = {};
        if (more) {
            t0 = *(const uint4*)(Kg + (size_t)(jt + 128 + krow) * 32 + kcol);
            t1 = *(const uint4*)(Kg + (size_t)(jt + 192 + krow) * 32 + kcol);
            t2 = *(const uint4*)(Vg + (size_t)vd * 512 + jt + 128 + vn);
            t3 = *(const uint4*)(Vg + (size_t)(16 + vd) * 512 + jt + 128 + vn);
        }
        // ---- batch the A C-operand loads for this jt ----
        uint2 ar[16];
#pragma unroll
        for (int mt = 0; mt < 8; ++mt) {
            ar[2*mt]     = *(const uint2*)(Ar0 + jt + mt * 16);
            ar[2*mt + 1] = *(const uint2*)(Ar1 + jt + mt * 16);
        }

        float ps0 = 0.f, ps1 = 0.f;
#pragma unroll
        for (int ks = 0; ks < 4; ++ks) {
            // ---- S chunk: keys ks*32 .. +31 (mt = 2ks, 2ks+1) ----
#pragma unroll
            for (int mm = 0; mm < 2; ++mm) {
                const int mt = 2 * ks + mm;
                short8 ka = *(const short8*)&Ks[cur][(mt * 16 + ln) * 40 + quad * 8];
                f32x4 c0, c1;
                c0[0] = __uint_as_float(ar[2*mt].x << 16);   c0[1] = __uint_as_float(ar[2*mt].x & 0xffff0000u);
                c0[2] = __uint_as_float(ar[2*mt].y << 16);   c0[3] = __uint_as_float(ar[2*mt].y & 0xffff0000u);
                c1[0] = __uint_as_float(ar[2*mt+1].x << 16); c1[1] = __uint_as_float(ar[2*mt+1].x & 0xffff0000u);
                c1[2] = __uint_as_float(ar[2*mt+1].y << 16); c1[3] = __uint_as_float(ar[2*mt+1].y & 0xffff0000u);
                const f32x4 s0 = __builtin_amdgcn_mfma_f32_16x16x32_bf16(ka, qf[0], c0, 0, 0, 0);
                const f32x4 s1 = __builtin_amdgcn_mfma_f32_16x16x32_bf16(ka, qf[1], c1, 0, 0, 0);
                const float p00 = __expf(s0[0]), p01 = __expf(s0[1]), p02 = __expf(s0[2]), p03 = __expf(s0[3]);
                const float p10 = __expf(s1[0]), p11 = __expf(s1[1]), p12 = __expf(s1[2]), p13 = __expf(s1[3]);
                ps0 += (p00 + p01) + (p02 + p03);
                ps1 += (p10 + p11) + (p12 + p13);
                uint2 w0; w0.x = pk2(p00, p01); w0.y = pk2(p02, p03);
                uint2 w1; w1.x = pk2(p10, p11); w1.y = pk2(p12, p13);
                *(uint2*)&Ps[w][ln * 40 + mm * 16 + quad * 4]        = w0;
                *(uint2*)&Ps[w][(16 + ln) * 40 + mm * 16 + quad * 4] = w1;
            }
            // ---- PV chunk (within-wave LDS dependency only) ----
            short8 pa0 = *(const short8*)&Ps[w][ln * 40 + quad * 8];
            short8 pa1 = *(const short8*)&Ps[w][(16 + ln) * 40 + quad * 8];
            short8 vb0 = *(const short8*)&Vs[cur][ln * 136 + ks * 32 + quad * 8];
            short8 vb1 = *(const short8*)&Vs[cur][(16 + ln) * 136 + ks * 32 + quad * 8];
            o[0][0] = __builtin_amdgcn_mfma_f32_16x16x32_bf16(pa0, vb0, o[0][0], 0, 0, 0);
            o[0][1] = __builtin_amdgcn_mfma_f32_16x16x32_bf16(pa0, vb1, o[0][1], 0, 0, 0);
            o[1][0] = __builtin_amdgcn_mfma_f32_16x16x32_bf16(pa1, vb0, o[1][0], 0, 0, 0);
            o[1][1] = __builtin_amdgcn_mfma_f32_16x16x32_bf16(pa1, vb1, o[1][1], 0, 0, 0);
        }

        // ---- write staged regs -> next buffer, single barrier per jt ----
        if (more) {
            *(uint4*)&Ks[nxt][krow * 40 + kcol]        = t0;
            *(uint4*)&Ks[nxt][(64 + krow) * 40 + kcol] = t1;
            *(uint4*)&Vs[nxt][vd * 136 + vn]           = t2;
            *(uint4*)&Vs[nxt][(16 + vd) * 136 + vn]    = t3;
        }
        ps0 += __shfl_xor(ps0, 16); ps0 += __shfl_xor(ps0, 32); lsum0 += ps0;
        ps1 += __shfl_xor(ps1, 16); ps1 += __shfl_xor(ps1, 32); lsum1 += ps1;
        __syncthreads();
        cur = nxt;
    }

    // ---- epilogue: O /= l, heads back to [BT,N,D] bf16 ----
#pragma unroll
    for (int r = 0; r < 4; ++r) {
        const int src = quad * 4 + r;
        const float i0 = 1.f / __shfl(lsum0, src);
        const float i1 = 1.f / __shfl(lsum1, src);
        const int n0 = qt * 128 + w * 32 + quad * 4 + r;
#pragma unroll
        for (int ntd = 0; ntd < 2; ++ntd) {
            AO[((size_t)bt * 512 + n0) * 256 + h * 32 + ntd * 16 + ln]      = f2b(o[0][ntd][r] * i0);
            AO[((size_t)bt * 512 + n0 + 16) * 256 + h * 32 + ntd * 16 + ln] = f2b(o[1][ntd][r] * i1);
        }
    }
}

// ---------------- Kernel 3: output projection + bias ----------------
__global__ __launch_bounds__(256) void proj_gemm(const u16* __restrict__ X,
                                                 const float* __restrict__ W,
                                                 const float* __restrict__ BIAS,
                                                 float* __restrict__ OUT) {
    __shared__ u16 Xs[128 * LDK];
    __shared__ u16 Ws[128 * LDK];
    const int t    = threadIdx.x;
    const int m0   = blockIdx.x << 7;
    const int o0   = blockIdx.y << 7;
    const int lane = t & 63;
    const int wid  = t >> 6;
    const int wr   = (wid >> 1) << 6;
    const int wc   = (wid & 1) << 6;
    const int ln   = lane & 15;
    const int quad = lane >> 4;

    const int r  = t >> 1;
    const int hf = (t & 1) << 5;
    const u16*   xg = X + (size_t)(m0 + r) * 256 + hf;
    const float* wg = W + (size_t)(o0 + r) * 256 + hf;
    uint4* xls = (uint4*)&Xs[r * LDK + hf];
    uint4* wls = (uint4*)&Ws[r * LDK + hf];

    f32x4 acc[4][4] = {};

    for (int kc = 0; kc < 256; kc += 64) {
        const uint4*  xp = (const uint4*)(xg + kc);
        const float4* wp = (const float4*)(wg + kc);
        uint4 x0 = xp[0], x1 = xp[1], x2 = xp[2], x3 = xp[3];
        float wv[32];
#pragma unroll
        for (int i = 0; i < 8; ++i) {
            float4 b = wp[i]; wv[4*i] = b.x; wv[4*i+1] = b.y; wv[4*i+2] = b.z; wv[4*i+3] = b.w;
        }
        uint4 wq[4];
#pragma unroll
        for (int i = 0; i < 4; ++i) {
            wq[i].x = pk2(wv[8*i],   wv[8*i+1]); wq[i].y = pk2(wv[8*i+2], wv[8*i+3]);
            wq[i].z = pk2(wv[8*i+4], wv[8*i+5]); wq[i].w = pk2(wv[8*i+6], wv[8*i+7]);
        }
        __syncthreads();
        xls[0] = x0; xls[1] = x1; xls[2] = x2; xls[3] = x3;
#pragma unroll
        for (int i = 0; i < 4; ++i) wls[i] = wq[i];
        __syncthreads();
#pragma unroll
        for (int kk = 0; kk < 64; kk += 32) {
            short8 a[4], b[4];
#pragma unroll
            for (int i = 0; i < 4; ++i)
                a[i] = *(const short8*)&Xs[(wr + i * 16 + ln) * LDK + kk + quad * 8];
#pragma unroll
            for (int j = 0; j < 4; ++j)
                b[j] = *(const short8*)&Ws[(wc + j * 16 + ln) * LDK + kk + quad * 8];
#pragma unroll
            for (int i = 0; i < 4; ++i)
#pragma unroll
                for (int j = 0; j < 4; ++j)
                    acc[i][j] = __builtin_amdgcn_mfma_f32_16x16x32_bf16(a[i], b[j], acc[i][j], 0, 0, 0);
        }
    }

#pragma unroll
    for (int i = 0; i < 4; ++i) {
        const int mb = m0 + wr + i * 16 + quad * 4;
#pragma unroll
        for (int j = 0; j < 4; ++j) {
            const int o  = o0 + wc + j * 16 + ln;
            const float bo = BIAS[o];
#pragma unroll
            for (int rr = 0; rr < 4; ++rr) {
                const int m = mb + rr;
                OUT[(size_t)m * 256 + o] = acc[i][j][rr] + bo;
            }
        }
    }
}

extern "C" void kernel_launch(void* const* d_in, const int* in_sizes, int n_in,
                              void* d_out, int out_size, void* d_ws, size_t ws_size,
                              hipStream_t stream) {
    (void)in_sizes; (void)n_in; (void)out_size; (void)ws_size;
    const float* x     = (const float*)d_in[0];   // [32,512,256] fp32
    const float* A     = (const float*)d_in[1];   // [4,512,512]  fp32
    const float* Wqkv  = (const float*)d_in[2];   // [768,256]    fp32
    const float* Wproj = (const float*)d_in[3];   // [256,256]    fp32
    const float* bproj = (const float*)d_in[4];   // [256]        fp32
    const float* lam   = (const float*)d_in[5];   // [1]          fp32
    const int*   nf    = (const int*)d_in[6];     // [1]          int32
    float* out = (float*)d_out;                   // [32,512,256] fp32

    // ws: q,k [bh,n,hd] + vt [bh,hd,n] bf16 (8MB each) + ao (8MB) + AB lambda*A bf16 (2MB) = 34MB
    u16* q  = (u16*)d_ws;
    u16* k  = q + 4194304;
    u16* vt = k + 4194304;
    u16* ao = vt + 4194304;
    u16* AB = ao + 4194304;

    prep_A  <<<dim3(512), 256, 0, stream>>>(A, lam, AB);
    qkv_gemm<<<dim3(128, 6), 256, 0, stream>>>(x, Wqkv, q, k, vt);
    attn_mfma<<<dim3(1024), 256, 0, stream>>>(q, k, vt, AB, nf, ao);
    proj_gemm<<<dim3(128, 2), 256, 0, stream>>>(ao, Wproj, bproj, out);
}

// Round 9
// 161.430 us; speedup vs baseline: 1.1039x; 1.0415x over previous
//
#include <hip/hip_runtime.h>
#include <hip/hip_bf16.h>

typedef unsigned short u16;
typedef unsigned int   u32;
typedef __attribute__((ext_vector_type(8))) short short8;
typedef __attribute__((ext_vector_type(4))) float f32x4;

static __device__ __forceinline__ u16 f2b(float f) {
    __hip_bfloat16 h = __float2bfloat16(f);
    return *reinterpret_cast<u16*>(&h);
}
static __device__ __forceinline__ u32 pk2(float a, float b) {
    return (u32)f2b(a) | ((u32)f2b(b) << 16);
}

#define LDK 72  // GEMM LDS row stride (bf16): 144B rows, 16B-aligned, 2-way-max bank aliasing (free)

// ---------------- Kernel 0: prep — AB = lambda*A (bf16), Wqkv/Wproj -> bf16 ----------------
// ranges: blocks 0..511 -> A (1,048,576), 512..607 -> Wqkv (196,608), 608..639 -> Wproj (65,536)
__global__ __launch_bounds__(256) void prep(const float* __restrict__ A,
                                            const float* __restrict__ LAM,
                                            const float* __restrict__ Wq,
                                            const float* __restrict__ Wp,
                                            u16* __restrict__ AB,
                                            u16* __restrict__ wqb,
                                            u16* __restrict__ wpb) {
    const int bid = blockIdx.x;
    const float* src;
    u16* dst;
    float scale;
    int base;
    if (bid < 512)      { src = A;  dst = AB;  scale = LAM[0]; base = bid * 2048; }
    else if (bid < 608) { src = Wq; dst = wqb; scale = 1.0f;   base = (bid - 512) * 2048; }
    else                { src = Wp; dst = wpb; scale = 1.0f;   base = (bid - 608) * 2048; }
    const int i = base + threadIdx.x * 8;
    const float4 a = *(const float4*)(src + i);
    const float4 b = *(const float4*)(src + i + 4);
    uint4 o;
    o.x = pk2(scale * a.x, scale * a.y);
    o.y = pk2(scale * a.z, scale * a.w);
    o.z = pk2(scale * b.x, scale * b.y);
    o.w = pk2(scale * b.z, scale * b.w);
    *(uint4*)(dst + i) = o;
}

// ---------------- Kernel 1: QKV projection (X fp32, W pre-converted bf16) ----------------
__global__ __launch_bounds__(256) void qkv_gemm(const float* __restrict__ X,
                                                const u16* __restrict__ WB,
                                                u16* __restrict__ qo,
                                                u16* __restrict__ ko,
                                                u16* __restrict__ vt) {
    __shared__ u16 SH[2 * 128 * LDK];   // Xs | Ws; reused as transpose buf in v-epilogue
    u16* Xs = SH;
    u16* Ws = SH + 128 * LDK;
    const int t    = threadIdx.x;
    const int m0   = blockIdx.x << 7;
    const int o0   = blockIdx.y << 7;
    const int lane = t & 63;
    const int wid  = t >> 6;
    const int wr   = (wid >> 1) << 6;
    const int wc   = (wid & 1) << 6;
    const int ln   = lane & 15;
    const int quad = lane >> 4;

    const int r  = t >> 1;
    const int hf = (t & 1) << 5;
    const float* xg = X + (size_t)(m0 + r) * 256 + hf;
    const u16*   wg = WB + (size_t)(o0 + r) * 256 + hf;
    uint4* xls = (uint4*)&Xs[r * LDK + hf];
    uint4* wls = (uint4*)&Ws[r * LDK + hf];

    f32x4 acc[4][4] = {};

    for (int kc = 0; kc < 256; kc += 64) {
        const float4* xp = (const float4*)(xg + kc);
        const uint4*  wp = (const uint4*)(wg + kc);
        float xv[32];
#pragma unroll
        for (int i = 0; i < 8; ++i) {
            float4 a = xp[i]; xv[4*i] = a.x; xv[4*i+1] = a.y; xv[4*i+2] = a.z; xv[4*i+3] = a.w;
        }
        uint4 w0 = wp[0], w1 = wp[1], w2 = wp[2], w3 = wp[3];
        uint4 xq[4];
#pragma unroll
        for (int i = 0; i < 4; ++i) {
            xq[i].x = pk2(xv[8*i],   xv[8*i+1]); xq[i].y = pk2(xv[8*i+2], xv[8*i+3]);
            xq[i].z = pk2(xv[8*i+4], xv[8*i+5]); xq[i].w = pk2(xv[8*i+6], xv[8*i+7]);
        }
        __syncthreads();
#pragma unroll
        for (int i = 0; i < 4; ++i) xls[i] = xq[i];
        wls[0] = w0; wls[1] = w1; wls[2] = w2; wls[3] = w3;
        __syncthreads();
#pragma unroll
        for (int kk = 0; kk < 64; kk += 32) {
            short8 a[4], b[4];
#pragma unroll
            for (int i = 0; i < 4; ++i)
                a[i] = *(const short8*)&Xs[(wr + i * 16 + ln) * LDK + kk + quad * 8];
#pragma unroll
            for (int j = 0; j < 4; ++j)
                b[j] = *(const short8*)&Ws[(wc + j * 16 + ln) * LDK + kk + quad * 8];
#pragma unroll
            for (int i = 0; i < 4; ++i)
#pragma unroll
                for (int j = 0; j < 4; ++j)
                    acc[i][j] = __builtin_amdgcn_mfma_f32_16x16x32_bf16(a[i], b[j], acc[i][j], 0, 0, 0);
        }
    }

    const int which = o0 >> 8;  // 0=q, 1=k, 2=v
    if (which < 2) {
        const float qscale = (which == 0) ? 0.17677669529663689f : 1.0f;  // 32^-0.5 folded into q
        u16* dst = (which == 0) ? qo : ko;
#pragma unroll
        for (int i = 0; i < 4; ++i) {
            const int mb = m0 + wr + i * 16 + quad * 4;  // C/D: row = quad*4 + reg
#pragma unroll
            for (int j = 0; j < 4; ++j) {
                const int o   = o0 + wc + j * 16 + ln;   // C/D: col = lane&15
                const int rem = o & 255;
                const int hh  = rem >> 5;
                const int dd  = rem & 31;
#pragma unroll
                for (int rr = 0; rr < 4; ++rr) {
                    const int m  = mb + rr;
                    const int bt = m >> 9;
                    const int n  = m & 511;
                    dst[(((size_t)bt * 8 + hh) * 512 + n) * 32 + dd] = f2b(acc[i][j][rr] * qscale);
                }
            }
        }
    } else {
        // v: transpose 128m x 128o tile via LDS, packed 16B stores to vt[bh][dd][n]
        __syncthreads();
        u16* T = SH;                           // 128 rows (o_local) x stride 136 (m_local)
#pragma unroll
        for (int i = 0; i < 4; ++i) {
            const int ml = wr + i * 16 + quad * 4;
#pragma unroll
            for (int j = 0; j < 4; ++j) {
                const int ol = wc + j * 16 + ln;
                uint2 pv;
                pv.x = pk2(acc[i][j][0], acc[i][j][1]);
                pv.y = pk2(acc[i][j][2], acc[i][j][3]);
                *(uint2*)&T[ol * 136 + ml] = pv;
            }
        }
        __syncthreads();
        const int row = t >> 1;
        const int seg = (t & 1) << 6;
        const int o   = o0 + row;
        const int rem = o & 255;
        const int hh  = rem >> 5;
        const int dd  = rem & 31;
        const int bt  = m0 >> 9;
        u16* dstv = vt + (((size_t)bt * 8 + hh) * 32 + dd) * 512 + (m0 & 511) + seg;
#pragma unroll
        for (int kk2 = 0; kk2 < 8; ++kk2) {
            uint4 val = *(const uint4*)&T[row * 136 + seg + kk2 * 8];
            *(uint4*)(dstv + kk2 * 8) = val;
        }
    }
}

// ---------------- Kernel 2: MFMA flash attention — LDS dbuf + cross-barrier A prefetch ----------------
// K/V staged once per block per jt (dbuf, one barrier). A C-operand regs double-buffered ACROSS
// the barrier (the barrier fences memory ops -> allocator cannot sink the prefetch to its use).
__global__ __launch_bounds__(256, 3) void attn_mfma(const u16* __restrict__ Q,
                                                    const u16* __restrict__ K,
                                                    const u16* __restrict__ VT,
                                                    const u16* __restrict__ AB,
                                                    const int* __restrict__ NF,
                                                    u16* __restrict__ AO) {
    __shared__ u16 Ks[2][128 * 40];   // [buf][key][dim]  80B rows
    __shared__ u16 Vs[2][32 * 136];   // [buf][dim][key]  272B rows
    __shared__ u16 Ps[4][32 * 40];    // per-wave P^T chunk [q][32 keys]
    const int t    = threadIdx.x;
    const int w    = t >> 6;
    const int lane = t & 63;
    const int ln   = lane & 15;
    const int quad = lane >> 4;
    // XCD swizzle: blocks sharing an A-tile keep blockIdx%8 invariant
    const int L    = blockIdx.x;
    const int g    = (L & 7) + (((L >> 3) & 1) << 3);  // 0..15
    const int j    = L >> 4;                           // 0..63
    const int qt   = g & 3;
    const int h    = j & 7;
    const int bt   = (g >> 2) * 8 + (j >> 3);
    const int bh   = bt * 8 + h;
    const int q0   = qt * 128 + w * 32;
    const size_t base = (size_t)bh * (512 * 32);
    const int b    = bt / NF[0];
    const u16* Ab  = AB + (size_t)b * 512 * 512;
    const u16* Ar0 = Ab + (size_t)(q0 + ln) * 512 + quad * 4;
    const u16* Ar1 = Ab + (size_t)(q0 + 16 + ln) * 512 + quad * 4;

    // cooperative staging map (4096 bf16 per tile, 256 threads, 2x uint4 each)
    const int krow = t >> 2, kcol = (t & 3) * 8;   // K rows krow / krow+64
    const int vd   = t >> 4, vn   = (t & 15) * 8;  // VT dims vd / vd+16
    const u16* Kg = K + base;
    const u16* Vg = VT + base;

    // ---- prologue: stage jt=0 + preload A regs for jt=0 ----
    {
        uint4 s0 = *(const uint4*)(Kg + (size_t)krow * 32 + kcol);
        uint4 s1 = *(const uint4*)(Kg + (size_t)(64 + krow) * 32 + kcol);
        uint4 s2 = *(const uint4*)(Vg + (size_t)vd * 512 + vn);
        uint4 s3 = *(const uint4*)(Vg + (size_t)(16 + vd) * 512 + vn);
        *(uint4*)&Ks[0][krow * 40 + kcol]        = s0;
        *(uint4*)&Ks[0][(64 + krow) * 40 + kcol] = s1;
        *(uint4*)&Vs[0][vd * 136 + vn]           = s2;
        *(uint4*)&Vs[0][(16 + vd) * 136 + vn]    = s3;
    }
    uint2 ar[16];
#pragma unroll
    for (int mt = 0; mt < 8; ++mt) {
        ar[2*mt]     = *(const uint2*)(Ar0 + mt * 16);
        ar[2*mt + 1] = *(const uint2*)(Ar1 + mt * 16);
    }

    short8 qf[2];
#pragma unroll
    for (int nt = 0; nt < 2; ++nt)
        qf[nt] = *(const short8*)(Q + base + (size_t)(q0 + nt * 16 + ln) * 32 + quad * 8);

    f32x4 o[2][2] = {};            // O[q-tile][dim-tile], C-layout
    float lsum0 = 0.f, lsum1 = 0.f;
    __syncthreads();

    int cur = 0;
    for (int jt = 0; jt < 512; jt += 128) {
        const int nxt = cur ^ 1;
        const int jn  = (jt + 128) & 511;   // wrapped: last iter stages tile 0 (unused, harmless)
        // ---- stage next K/V tile into regs (consumed after compute -> full phase of slack) ----
        uint4 t0 = *(const uint4*)(Kg + (size_t)(jn + krow) * 32 + kcol);
        uint4 t1 = *(const uint4*)(Kg + (size_t)(jn + 64 + krow) * 32 + kcol);
        uint4 t2 = *(const uint4*)(Vg + (size_t)vd * 512 + jn + vn);
        uint4 t3 = *(const uint4*)(Vg + (size_t)(16 + vd) * 512 + jn + vn);
        // ---- prefetch NEXT jt's A C-operands (used after the barrier; barrier fences sinking) ----
        uint2 arn[16];
#pragma unroll
        for (int mt = 0; mt < 8; ++mt) {
            arn[2*mt]     = *(const uint2*)(Ar0 + jn + mt * 16);
            arn[2*mt + 1] = *(const uint2*)(Ar1 + jn + mt * 16);
        }

        float ps0 = 0.f, ps1 = 0.f;
#pragma unroll
        for (int ks = 0; ks < 4; ++ks) {
            // ---- S chunk: keys ks*32 .. +31 (mt = 2ks, 2ks+1) ----
#pragma unroll
            for (int mm = 0; mm < 2; ++mm) {
                const int mt = 2 * ks + mm;
                short8 ka = *(const short8*)&Ks[cur][(mt * 16 + ln) * 40 + quad * 8];
                f32x4 c0, c1;
                c0[0] = __uint_as_float(ar[2*mt].x << 16);   c0[1] = __uint_as_float(ar[2*mt].x & 0xffff0000u);
                c0[2] = __uint_as_float(ar[2*mt].y << 16);   c0[3] = __uint_as_float(ar[2*mt].y & 0xffff0000u);
                c1[0] = __uint_as_float(ar[2*mt+1].x << 16); c1[1] = __uint_as_float(ar[2*mt+1].x & 0xffff0000u);
                c1[2] = __uint_as_float(ar[2*mt+1].y << 16); c1[3] = __uint_as_float(ar[2*mt+1].y & 0xffff0000u);
                const f32x4 s0 = __builtin_amdgcn_mfma_f32_16x16x32_bf16(ka, qf[0], c0, 0, 0, 0);
                const f32x4 s1 = __builtin_amdgcn_mfma_f32_16x16x32_bf16(ka, qf[1], c1, 0, 0, 0);
                const float p00 = __expf(s0[0]), p01 = __expf(s0[1]), p02 = __expf(s0[2]), p03 = __expf(s0[3]);
                const float p10 = __expf(s1[0]), p11 = __expf(s1[1]), p12 = __expf(s1[2]), p13 = __expf(s1[3]);
                ps0 += (p00 + p01) + (p02 + p03);
                ps1 += (p10 + p11) + (p12 + p13);
                uint2 w0; w0.x = pk2(p00, p01); w0.y = pk2(p02, p03);
                uint2 w1; w1.x = pk2(p10, p11); w1.y = pk2(p12, p13);
                *(uint2*)&Ps[w][ln * 40 + mm * 16 + quad * 4]        = w0;
                *(uint2*)&Ps[w][(16 + ln) * 40 + mm * 16 + quad * 4] = w1;
            }
            // ---- PV chunk (within-wave LDS dependency only) ----
            short8 pa0 = *(const short8*)&Ps[w][ln * 40 + quad * 8];
            short8 pa1 = *(const short8*)&Ps[w][(16 + ln) * 40 + quad * 8];
            short8 vb0 = *(const short8*)&Vs[cur][ln * 136 + ks * 32 + quad * 8];
            short8 vb1 = *(const short8*)&Vs[cur][(16 + ln) * 136 + ks * 32 + quad * 8];
            o[0][0] = __builtin_amdgcn_mfma_f32_16x16x32_bf16(pa0, vb0, o[0][0], 0, 0, 0);
            o[0][1] = __builtin_amdgcn_mfma_f32_16x16x32_bf16(pa0, vb1, o[0][1], 0, 0, 0);
            o[1][0] = __builtin_amdgcn_mfma_f32_16x16x32_bf16(pa1, vb0, o[1][0], 0, 0, 0);
            o[1][1] = __builtin_amdgcn_mfma_f32_16x16x32_bf16(pa1, vb1, o[1][1], 0, 0, 0);
        }

        // ---- write staged regs -> next buffer, single barrier per jt ----
        *(uint4*)&Ks[nxt][krow * 40 + kcol]        = t0;
        *(uint4*)&Ks[nxt][(64 + krow) * 40 + kcol] = t1;
        *(uint4*)&Vs[nxt][vd * 136 + vn]           = t2;
        *(uint4*)&Vs[nxt][(16 + vd) * 136 + vn]    = t3;
        ps0 += __shfl_xor(ps0, 16); ps0 += __shfl_xor(ps0, 32); lsum0 += ps0;
        ps1 += __shfl_xor(ps1, 16); ps1 += __shfl_xor(ps1, 32); lsum1 += ps1;
        __syncthreads();
#pragma unroll
        for (int i = 0; i < 16; ++i) ar[i] = arn[i];
        cur = nxt;
    }

    // ---- epilogue: O /= l, heads back to [BT,N,D] bf16 ----
#pragma unroll
    for (int r = 0; r < 4; ++r) {
        const int src = quad * 4 + r;
        const float i0 = 1.f / __shfl(lsum0, src);
        const float i1 = 1.f / __shfl(lsum1, src);
        const int n0 = qt * 128 + w * 32 + quad * 4 + r;
#pragma unroll
        for (int ntd = 0; ntd < 2; ++ntd) {
            AO[((size_t)bt * 512 + n0) * 256 + h * 32 + ntd * 16 + ln]      = f2b(o[0][ntd][r] * i0);
            AO[((size_t)bt * 512 + n0 + 16) * 256 + h * 32 + ntd * 16 + ln] = f2b(o[1][ntd][r] * i1);
        }
    }
}

// ---------------- Kernel 3: output projection + bias (W pre-converted bf16) ----------------
__global__ __launch_bounds__(256) void proj_gemm(const u16* __restrict__ X,
                                                 const u16* __restrict__ WB,
                                                 const float* __restrict__ BIAS,
                                                 float* __restrict__ OUT) {
    __shared__ u16 Xs[128 * LDK];
    __shared__ u16 Ws[128 * LDK];
    const int t    = threadIdx.x;
    const int m0   = blockIdx.x << 7;
    const int o0   = blockIdx.y << 7;
    const int lane = t & 63;
    const int wid  = t >> 6;
    const int wr   = (wid >> 1) << 6;
    const int wc   = (wid & 1) << 6;
    const int ln   = lane & 15;
    const int quad = lane >> 4;

    const int r  = t >> 1;
    const int hf = (t & 1) << 5;
    const u16* xg = X + (size_t)(m0 + r) * 256 + hf;
    const u16* wg = WB + (size_t)(o0 + r) * 256 + hf;
    uint4* xls = (uint4*)&Xs[r * LDK + hf];
    uint4* wls = (uint4*)&Ws[r * LDK + hf];

    f32x4 acc[4][4] = {};

    for (int kc = 0; kc < 256; kc += 64) {
        const uint4* xp = (const uint4*)(xg + kc);
        const uint4* wp = (const uint4*)(wg + kc);
        uint4 x0 = xp[0], x1 = xp[1], x2 = xp[2], x3 = xp[3];
        uint4 w0 = wp[0], w1 = wp[1], w2 = wp[2], w3 = wp[3];
        __syncthreads();
        xls[0] = x0; xls[1] = x1; xls[2] = x2; xls[3] = x3;
        wls[0] = w0; wls[1] = w1; wls[2] = w2; wls[3] = w3;
        __syncthreads();
#pragma unroll
        for (int kk = 0; kk < 64; kk += 32) {
            short8 a[4], b[4];
#pragma unroll
            for (int i = 0; i < 4; ++i)
                a[i] = *(const short8*)&Xs[(wr + i * 16 + ln) * LDK + kk + quad * 8];
#pragma unroll
            for (int j = 0; j < 4; ++j)
                b[j] = *(const short8*)&Ws[(wc + j * 16 + ln) * LDK + kk + quad * 8];
#pragma unroll
            for (int i = 0; i < 4; ++i)
#pragma unroll
                for (int j = 0; j < 4; ++j)
                    acc[i][j] = __builtin_amdgcn_mfma_f32_16x16x32_bf16(a[i], b[j], acc[i][j], 0, 0, 0);
        }
    }

#pragma unroll
    for (int i = 0; i < 4; ++i) {
        const int mb = m0 + wr + i * 16 + quad * 4;
#pragma unroll
        for (int j = 0; j < 4; ++j) {
            const int o  = o0 + wc + j * 16 + ln;
            const float bo = BIAS[o];
#pragma unroll
            for (int rr = 0; rr < 4; ++rr) {
                const int m = mb + rr;
                OUT[(size_t)m * 256 + o] = acc[i][j][rr] + bo;
            }
        }
    }
}

extern "C" void kernel_launch(void* const* d_in, const int* in_sizes, int n_in,
                              void* d_out, int out_size, void* d_ws, size_t ws_size,
                              hipStream_t stream) {
    (void)in_sizes; (void)n_in; (void)out_size; (void)ws_size;
    const float* x     = (const float*)d_in[0];   // [32,512,256] fp32
    const float* A     = (const float*)d_in[1];   // [4,512,512]  fp32
    const float* Wqkv  = (const float*)d_in[2];   // [768,256]    fp32
    const float* Wproj = (const float*)d_in[3];   // [256,256]    fp32
    const float* bproj = (const float*)d_in[4];   // [256]        fp32
    const float* lam   = (const float*)d_in[5];   // [1]          fp32
    const int*   nf    = (const int*)d_in[6];     // [1]          int32
    float* out = (float*)d_out;                   // [32,512,256] fp32

    // ws (u16 units): q,k,vt (4,194,304 each) + ao (4,194,304) + AB (1,048,576)
    //                + wqb (196,608) + wpb (65,536) = ~36.2 MB
    u16* q   = (u16*)d_ws;
    u16* k   = q + 4194304;
    u16* vt  = k + 4194304;
    u16* ao  = vt + 4194304;
    u16* AB  = ao + 4194304;
    u16* wqb = AB + 1048576;
    u16* wpb = wqb + 196608;

    prep    <<<dim3(640), 256, 0, stream>>>(A, lam, Wqkv, Wproj, AB, wqb, wpb);
    qkv_gemm<<<dim3(128, 6), 256, 0, stream>>>(x, wqb, q, k, vt);
    attn_mfma<<<dim3(1024), 256, 0, stream>>>(q, k, vt, AB, nf, ao);
    proj_gemm<<<dim3(128, 2), 256, 0, stream>>>(ao, wpb, bproj, out);
}

// Round 10
// 154.117 us; speedup vs baseline: 1.1563x; 1.0474x over previous
//
#include <hip/hip_runtime.h>
#include <hip/hip_bf16.h>

typedef unsigned short u16;
typedef unsigned int   u32;
typedef __attribute__((ext_vector_type(8))) short short8;
typedef __attribute__((ext_vector_type(4))) float f32x4;

static __device__ __forceinline__ u16 f2b(float f) {
    __hip_bfloat16 h = __float2bfloat16(f);
    return *reinterpret_cast<u16*>(&h);
}
static __device__ __forceinline__ u32 pk2(float a, float b) {
    return (u32)f2b(a) | ((u32)f2b(b) << 16);
}

#define LDK 72  // GEMM LDS row stride (bf16): 144B rows, 16B-aligned, 2-way-max bank aliasing (free)

// ---------------- Kernel 0: prep — AB = lambda*A (bf16), Wqkv/Wproj -> bf16 ----------------
__global__ __launch_bounds__(256) void prep(const float* __restrict__ A,
                                            const float* __restrict__ LAM,
                                            const float* __restrict__ Wq,
                                            const float* __restrict__ Wp,
                                            u16* __restrict__ AB,
                                            u16* __restrict__ wqb,
                                            u16* __restrict__ wpb) {
    const int bid = blockIdx.x;
    const float* src;
    u16* dst;
    float scale;
    int base;
    if (bid < 512)      { src = A;  dst = AB;  scale = LAM[0]; base = bid * 2048; }
    else if (bid < 608) { src = Wq; dst = wqb; scale = 1.0f;   base = (bid - 512) * 2048; }
    else                { src = Wp; dst = wpb; scale = 1.0f;   base = (bid - 608) * 2048; }
    const int i = base + threadIdx.x * 8;
    const float4 a = *(const float4*)(src + i);
    const float4 b = *(const float4*)(src + i + 4);
    uint4 o;
    o.x = pk2(scale * a.x, scale * a.y);
    o.y = pk2(scale * a.z, scale * a.w);
    o.z = pk2(scale * b.x, scale * b.y);
    o.w = pk2(scale * b.z, scale * b.w);
    *(uint4*)(dst + i) = o;
}

// ---------------- Kernel 1: QKV projection (X fp32, W pre-converted bf16) ----------------
__global__ __launch_bounds__(256) void qkv_gemm(const float* __restrict__ X,
                                                const u16* __restrict__ WB,
                                                u16* __restrict__ qo,
                                                u16* __restrict__ ko,
                                                u16* __restrict__ vt) {
    __shared__ u16 SH[2 * 128 * LDK];   // Xs | Ws; reused as transpose buf in v-epilogue
    u16* Xs = SH;
    u16* Ws = SH + 128 * LDK;
    const int t    = threadIdx.x;
    const int m0   = blockIdx.x << 7;
    const int o0   = blockIdx.y << 7;
    const int lane = t & 63;
    const int wid  = t >> 6;
    const int wr   = (wid >> 1) << 6;
    const int wc   = (wid & 1) << 6;
    const int ln   = lane & 15;
    const int quad = lane >> 4;

    const int r  = t >> 1;
    const int hf = (t & 1) << 5;
    const float* xg = X + (size_t)(m0 + r) * 256 + hf;
    const u16*   wg = WB + (size_t)(o0 + r) * 256 + hf;
    uint4* xls = (uint4*)&Xs[r * LDK + hf];
    uint4* wls = (uint4*)&Ws[r * LDK + hf];

    f32x4 acc[4][4] = {};

    for (int kc = 0; kc < 256; kc += 64) {
        const float4* xp = (const float4*)(xg + kc);
        const uint4*  wp = (const uint4*)(wg + kc);
        float xv[32];
#pragma unroll
        for (int i = 0; i < 8; ++i) {
            float4 a = xp[i]; xv[4*i] = a.x; xv[4*i+1] = a.y; xv[4*i+2] = a.z; xv[4*i+3] = a.w;
        }
        uint4 w0 = wp[0], w1 = wp[1], w2 = wp[2], w3 = wp[3];
        uint4 xq[4];
#pragma unroll
        for (int i = 0; i < 4; ++i) {
            xq[i].x = pk2(xv[8*i],   xv[8*i+1]); xq[i].y = pk2(xv[8*i+2], xv[8*i+3]);
            xq[i].z = pk2(xv[8*i+4], xv[8*i+5]); xq[i].w = pk2(xv[8*i+6], xv[8*i+7]);
        }
        __syncthreads();
#pragma unroll
        for (int i = 0; i < 4; ++i) xls[i] = xq[i];
        wls[0] = w0; wls[1] = w1; wls[2] = w2; wls[3] = w3;
        __syncthreads();
#pragma unroll
        for (int kk = 0; kk < 64; kk += 32) {
            short8 a[4], b[4];
#pragma unroll
            for (int i = 0; i < 4; ++i)
                a[i] = *(const short8*)&Xs[(wr + i * 16 + ln) * LDK + kk + quad * 8];
#pragma unroll
            for (int j = 0; j < 4; ++j)
                b[j] = *(const short8*)&Ws[(wc + j * 16 + ln) * LDK + kk + quad * 8];
#pragma unroll
            for (int i = 0; i < 4; ++i)
#pragma unroll
                for (int j = 0; j < 4; ++j)
                    acc[i][j] = __builtin_amdgcn_mfma_f32_16x16x32_bf16(a[i], b[j], acc[i][j], 0, 0, 0);
        }
    }

    const int which = o0 >> 8;  // 0=q, 1=k, 2=v
    if (which < 2) {
        const float qscale = (which == 0) ? 0.17677669529663689f : 1.0f;  // 32^-0.5 folded into q
        u16* dst = (which == 0) ? qo : ko;
#pragma unroll
        for (int i = 0; i < 4; ++i) {
            const int mb = m0 + wr + i * 16 + quad * 4;  // C/D: row = quad*4 + reg
#pragma unroll
            for (int j = 0; j < 4; ++j) {
                const int o   = o0 + wc + j * 16 + ln;   // C/D: col = lane&15
                const int rem = o & 255;
                const int hh  = rem >> 5;
                const int dd  = rem & 31;
#pragma unroll
                for (int rr = 0; rr < 4; ++rr) {
                    const int m  = mb + rr;
                    const int bt = m >> 9;
                    const int n  = m & 511;
                    dst[(((size_t)bt * 8 + hh) * 512 + n) * 32 + dd] = f2b(acc[i][j][rr] * qscale);
                }
            }
        }
    } else {
        // v: transpose 128m x 128o tile via LDS, packed 16B stores to vt[bh][dd][n]
        __syncthreads();
        u16* T = SH;                           // 128 rows (o_local) x stride 136 (m_local)
#pragma unroll
        for (int i = 0; i < 4; ++i) {
            const int ml = wr + i * 16 + quad * 4;
#pragma unroll
            for (int j = 0; j < 4; ++j) {
                const int ol = wc + j * 16 + ln;
                uint2 pv;
                pv.x = pk2(acc[i][j][0], acc[i][j][1]);
                pv.y = pk2(acc[i][j][2], acc[i][j][3]);
                *(uint2*)&T[ol * 136 + ml] = pv;
            }
        }
        __syncthreads();
        const int row = t >> 1;
        const int seg = (t & 1) << 6;
        const int o   = o0 + row;
        const int rem = o & 255;
        const int hh  = rem >> 5;
        const int dd  = rem & 31;
        const int bt  = m0 >> 9;
        u16* dstv = vt + (((size_t)bt * 8 + hh) * 32 + dd) * 512 + (m0 & 511) + seg;
#pragma unroll
        for (int kk2 = 0; kk2 < 8; ++kk2) {
            uint4 val = *(const uint4*)&T[row * 136 + seg + kk2 * 8];
            *(uint4*)(dstv + kk2 * 8) = val;
        }
    }
}

// ---------------- Kernel 2: MFMA flash attention — BK=64, LDS<32KB => all 1024 blocks resident ----------------
// r8/r9 ran as TWO waves-of-blocks (3 blocks/CU, 768+256) -> time = 2*T_block. LDS 29.7KB gives
// 4 blocks/CU fully resident in ONE round. Cooperative dbuf staging + A-reg dbuf carried over.
__global__ __launch_bounds__(256, 4) void attn_mfma(const u16* __restrict__ Q,
                                                    const u16* __restrict__ K,
                                                    const u16* __restrict__ VT,
                                                    const u16* __restrict__ AB,
                                                    const int* __restrict__ NF,
                                                    u16* __restrict__ AO) {
    __shared__ u16 Ks[2][64 * 40];    // [buf][key][dim]   80B rows
    __shared__ u16 Vs[2][32 * 72];    // [buf][dim][key]  144B rows (64 keys + 8 pad)
    __shared__ u16 Ps[4][32 * 40];    // per-wave P^T chunk [q][32 keys]
    const int t    = threadIdx.x;
    const int w    = t >> 6;
    const int lane = t & 63;
    const int ln   = lane & 15;
    const int quad = lane >> 4;
    // XCD swizzle: blocks sharing an A-tile keep blockIdx%8 invariant
    const int L    = blockIdx.x;
    const int g    = (L & 7) + (((L >> 3) & 1) << 3);  // 0..15
    const int j    = L >> 4;                           // 0..63
    const int qt   = g & 3;
    const int h    = j & 7;
    const int bt   = (g >> 2) * 8 + (j >> 3);
    const int bh   = bt * 8 + h;
    const int q0   = qt * 128 + w * 32;
    const size_t base = (size_t)bh * (512 * 32);
    const int b    = bt / NF[0];
    const u16* Ab  = AB + (size_t)b * 512 * 512;
    const u16* Ar0 = Ab + (size_t)(q0 + ln) * 512 + quad * 4;
    const u16* Ar1 = Ab + (size_t)(q0 + 16 + ln) * 512 + quad * 4;

    // cooperative staging map (2048 bf16 per tile, 256 threads, 1x uint4 each)
    const int krow = t >> 2, kcol = (t & 3) * 8;   // K: 64 rows x 32 dims
    const int vd   = t >> 3, vn   = (t & 7) * 8;   // VT: 32 dims x 64 keys
    const u16* Kg = K + base;
    const u16* Vg = VT + base;

    // ---- prologue: stage jt=0 + preload A regs for jt=0 ----
    {
        uint4 s0 = *(const uint4*)(Kg + (size_t)krow * 32 + kcol);
        uint4 s2 = *(const uint4*)(Vg + (size_t)vd * 512 + vn);
        *(uint4*)&Ks[0][krow * 40 + kcol] = s0;
        *(uint4*)&Vs[0][vd * 72 + vn]     = s2;
    }
    uint2 ar[8];
#pragma unroll
    for (int mt = 0; mt < 4; ++mt) {
        ar[2*mt]     = *(const uint2*)(Ar0 + mt * 16);
        ar[2*mt + 1] = *(const uint2*)(Ar1 + mt * 16);
    }

    short8 qf[2];
#pragma unroll
    for (int nt = 0; nt < 2; ++nt)
        qf[nt] = *(const short8*)(Q + base + (size_t)(q0 + nt * 16 + ln) * 32 + quad * 8);

    f32x4 o[2][2] = {};            // O[q-tile][dim-tile], C-layout
    float lsum0 = 0.f, lsum1 = 0.f;
    __syncthreads();

    int cur = 0;
    for (int jt = 0; jt < 512; jt += 64) {
        const int nxt = cur ^ 1;
        const int jn  = (jt + 64) & 511;   // wrapped: last iter stages tile 0 (unused, harmless)
        // ---- stage next K/V tile into regs (consumed after compute -> full phase of slack) ----
        uint4 t0 = *(const uint4*)(Kg + (size_t)(jn + krow) * 32 + kcol);
        uint4 t2 = *(const uint4*)(Vg + (size_t)vd * 512 + jn + vn);
        // ---- prefetch NEXT jt's A C-operands (used after the barrier -> cannot be sunk) ----
        uint2 arn[8];
#pragma unroll
        for (int mt = 0; mt < 4; ++mt) {
            arn[2*mt]     = *(const uint2*)(Ar0 + jn + mt * 16);
            arn[2*mt + 1] = *(const uint2*)(Ar1 + jn + mt * 16);
        }

        float ps0 = 0.f, ps1 = 0.f;
#pragma unroll
        for (int ks = 0; ks < 2; ++ks) {
            // ---- S chunk: keys ks*32 .. +31 (mt = 2ks, 2ks+1) ----
#pragma unroll
            for (int mm = 0; mm < 2; ++mm) {
                const int mt = 2 * ks + mm;
                short8 ka = *(const short8*)&Ks[cur][(mt * 16 + ln) * 40 + quad * 8];
                f32x4 c0, c1;
                c0[0] = __uint_as_float(ar[2*mt].x << 16);   c0[1] = __uint_as_float(ar[2*mt].x & 0xffff0000u);
                c0[2] = __uint_as_float(ar[2*mt].y << 16);   c0[3] = __uint_as_float(ar[2*mt].y & 0xffff0000u);
                c1[0] = __uint_as_float(ar[2*mt+1].x << 16); c1[1] = __uint_as_float(ar[2*mt+1].x & 0xffff0000u);
                c1[2] = __uint_as_float(ar[2*mt+1].y << 16); c1[3] = __uint_as_float(ar[2*mt+1].y & 0xffff0000u);
                const f32x4 s0 = __builtin_amdgcn_mfma_f32_16x16x32_bf16(ka, qf[0], c0, 0, 0, 0);
                const f32x4 s1 = __builtin_amdgcn_mfma_f32_16x16x32_bf16(ka, qf[1], c1, 0, 0, 0);
                const float p00 = __expf(s0[0]), p01 = __expf(s0[1]), p02 = __expf(s0[2]), p03 = __expf(s0[3]);
                const float p10 = __expf(s1[0]), p11 = __expf(s1[1]), p12 = __expf(s1[2]), p13 = __expf(s1[3]);
                ps0 += (p00 + p01) + (p02 + p03);
                ps1 += (p10 + p11) + (p12 + p13);
                uint2 w0; w0.x = pk2(p00, p01); w0.y = pk2(p02, p03);
                uint2 w1; w1.x = pk2(p10, p11); w1.y = pk2(p12, p13);
                *(uint2*)&Ps[w][ln * 40 + mm * 16 + quad * 4]        = w0;
                *(uint2*)&Ps[w][(16 + ln) * 40 + mm * 16 + quad * 4] = w1;
            }
            // ---- PV chunk (within-wave LDS dependency only) ----
            short8 pa0 = *(const short8*)&Ps[w][ln * 40 + quad * 8];
            short8 pa1 = *(const short8*)&Ps[w][(16 + ln) * 40 + quad * 8];
            short8 vb0 = *(const short8*)&Vs[cur][ln * 72 + ks * 32 + quad * 8];
            short8 vb1 = *(const short8*)&Vs[cur][(16 + ln) * 72 + ks * 32 + quad * 8];
            o[0][0] = __builtin_amdgcn_mfma_f32_16x16x32_bf16(pa0, vb0, o[0][0], 0, 0, 0);
            o[0][1] = __builtin_amdgcn_mfma_f32_16x16x32_bf16(pa0, vb1, o[0][1], 0, 0, 0);
            o[1][0] = __builtin_amdgcn_mfma_f32_16x16x32_bf16(pa1, vb0, o[1][0], 0, 0, 0);
            o[1][1] = __builtin_amdgcn_mfma_f32_16x16x32_bf16(pa1, vb1, o[1][1], 0, 0, 0);
        }

        // ---- write staged regs -> next buffer, single barrier per jt ----
        *(uint4*)&Ks[nxt][krow * 40 + kcol] = t0;
        *(uint4*)&Vs[nxt][vd * 72 + vn]     = t2;
        ps0 += __shfl_xor(ps0, 16); ps0 += __shfl_xor(ps0, 32); lsum0 += ps0;
        ps1 += __shfl_xor(ps1, 16); ps1 += __shfl_xor(ps1, 32); lsum1 += ps1;
        __syncthreads();
#pragma unroll
        for (int i = 0; i < 8; ++i) ar[i] = arn[i];
        cur = nxt;
    }

    // ---- epilogue: O /= l, heads back to [BT,N,D] bf16 ----
#pragma unroll
    for (int r = 0; r < 4; ++r) {
        const int src = quad * 4 + r;
        const float i0 = 1.f / __shfl(lsum0, src);
        const float i1 = 1.f / __shfl(lsum1, src);
        const int n0 = qt * 128 + w * 32 + quad * 4 + r;
#pragma unroll
        for (int ntd = 0; ntd < 2; ++ntd) {
            AO[((size_t)bt * 512 + n0) * 256 + h * 32 + ntd * 16 + ln]      = f2b(o[0][ntd][r] * i0);
            AO[((size_t)bt * 512 + n0 + 16) * 256 + h * 32 + ntd * 16 + ln] = f2b(o[1][ntd][r] * i1);
        }
    }
}

// ---------------- Kernel 3: output projection + bias (W pre-converted bf16) ----------------
__global__ __launch_bounds__(256) void proj_gemm(const u16* __restrict__ X,
                                                 const u16* __restrict__ WB,
                                                 const float* __restrict__ BIAS,
                                                 float* __restrict__ OUT) {
    __shared__ u16 Xs[128 * LDK];
    __shared__ u16 Ws[128 * LDK];
    const int t    = threadIdx.x;
    const int m0   = blockIdx.x << 7;
    const int o0   = blockIdx.y << 7;
    const int lane = t & 63;
    const int wid  = t >> 6;
    const int wr   = (wid >> 1) << 6;
    const int wc   = (wid & 1) << 6;
    const int ln   = lane & 15;
    const int quad = lane >> 4;

    const int r  = t >> 1;
    const int hf = (t & 1) << 5;
    const u16* xg = X + (size_t)(m0 + r) * 256 + hf;
    const u16* wg = WB + (size_t)(o0 + r) * 256 + hf;
    uint4* xls = (uint4*)&Xs[r * LDK + hf];
    uint4* wls = (uint4*)&Ws[r * LDK + hf];

    f32x4 acc[4][4] = {};

    for (int kc = 0; kc < 256; kc += 64) {
        const uint4* xp = (const uint4*)(xg + kc);
        const uint4* wp = (const uint4*)(wg + kc);
        uint4 x0 = xp[0], x1 = xp[1], x2 = xp[2], x3 = xp[3];
        uint4 w0 = wp[0], w1 = wp[1], w2 = wp[2], w3 = wp[3];
        __syncthreads();
        xls[0] = x0; xls[1] = x1; xls[2] = x2; xls[3] = x3;
        wls[0] = w0; wls[1] = w1; wls[2] = w2; wls[3] = w3;
        __syncthreads();
#pragma unroll
        for (int kk = 0; kk < 64; kk += 32) {
            short8 a[4], b[4];
#pragma unroll
            for (int i = 0; i < 4; ++i)
                a[i] = *(const short8*)&Xs[(wr + i * 16 + ln) * LDK + kk + quad * 8];
#pragma unroll
            for (int j = 0; j < 4; ++j)
                b[j] = *(const short8*)&Ws[(wc + j * 16 + ln) * LDK + kk + quad * 8];
#pragma unroll
            for (int i = 0; i < 4; ++i)
#pragma unroll
                for (int j = 0; j < 4; ++j)
                    acc[i][j] = __builtin_amdgcn_mfma_f32_16x16x32_bf16(a[i], b[j], acc[i][j], 0, 0, 0);
        }
    }

#pragma unroll
    for (int i = 0; i < 4; ++i) {
        const int mb = m0 + wr + i * 16 + quad * 4;
#pragma unroll
        for (int j = 0; j < 4; ++j) {
            const int o  = o0 + wc + j * 16 + ln;
            const float bo = BIAS[o];
#pragma unroll
            for (int rr = 0; rr < 4; ++rr) {
                const int m = mb + rr;
                OUT[(size_t)m * 256 + o] = acc[i][j][rr] + bo;
            }
        }
    }
}

extern "C" void kernel_launch(void* const* d_in, const int* in_sizes, int n_in,
                              void* d_out, int out_size, void* d_ws, size_t ws_size,
                              hipStream_t stream) {
    (void)in_sizes; (void)n_in; (void)out_size; (void)ws_size;
    const float* x     = (const float*)d_in[0];   // [32,512,256] fp32
    const float* A     = (const float*)d_in[1];   // [4,512,512]  fp32
    const float* Wqkv  = (const float*)d_in[2];   // [768,256]    fp32
    const float* Wproj = (const float*)d_in[3];   // [256,256]    fp32
    const float* bproj = (const float*)d_in[4];   // [256]        fp32
    const float* lam   = (const float*)d_in[5];   // [1]          fp32
    const int*   nf    = (const int*)d_in[6];     // [1]          int32
    float* out = (float*)d_out;                   // [32,512,256] fp32

    // ws (u16 units): q,k,vt (4,194,304 each) + ao (4,194,304) + AB (1,048,576)
    //                + wqb (196,608) + wpb (65,536)
    u16* q   = (u16*)d_ws;
    u16* k   = q + 4194304;
    u16* vt  = k + 4194304;
    u16* ao  = vt + 4194304;
    u16* AB  = ao + 4194304;
    u16* wqb = AB + 1048576;
    u16* wpb = wqb + 196608;

    prep    <<<dim3(640), 256, 0, stream>>>(A, lam, Wqkv, Wproj, AB, wqb, wpb);
    qkv_gemm<<<dim3(128, 6), 256, 0, stream>>>(x, wqb, q, k, vt);
    attn_mfma<<<dim3(1024), 256, 0, stream>>>(q, k, vt, AB, nf, ao);
    proj_gemm<<<dim3(128, 2), 256, 0, stream>>>(ao, wpb, bproj, out);
}

// Round 11
// 144.446 us; speedup vs baseline: 1.2337x; 1.0670x over previous
//
#include <hip/hip_runtime.h>
#include <hip/hip_bf16.h>

typedef unsigned short u16;
typedef unsigned int   u32;
typedef __attribute__((ext_vector_type(8))) short short8;
typedef __attribute__((ext_vector_type(4))) float f32x4;

static __device__ __forceinline__ u16 f2b(float f) {
    __hip_bfloat16 h = __float2bfloat16(f);
    return *reinterpret_cast<u16*>(&h);
}
static __device__ __forceinline__ u32 pk2(float a, float b) {
    return (u32)f2b(a) | ((u32)f2b(b) << 16);
}

#define LDK 72  // GEMM LDS row stride (bf16): 144B rows, 16B-aligned, 2-way-max bank aliasing (free)

// ---------------- Kernel 0: prep — X->bf16, AB = lambda*A (bf16), Wqkv/Wproj -> bf16 ----------------
// blocks: 0..2047 X (4,194,304), 2048..2559 A (1,048,576), 2560..2655 Wqkv (196,608), 2656..2687 Wproj (65,536)
__global__ __launch_bounds__(256) void prep(const float* __restrict__ X,
                                            const float* __restrict__ A,
                                            const float* __restrict__ LAM,
                                            const float* __restrict__ Wq,
                                            const float* __restrict__ Wp,
                                            u16* __restrict__ xb,
                                            u16* __restrict__ AB,
                                            u16* __restrict__ wqb,
                                            u16* __restrict__ wpb) {
    const int bid = blockIdx.x;
    const float* src;
    u16* dst;
    float scale;
    int base;
    if (bid < 2048)      { src = X;  dst = xb;  scale = 1.0f;   base = bid * 2048; }
    else if (bid < 2560) { src = A;  dst = AB;  scale = LAM[0]; base = (bid - 2048) * 2048; }
    else if (bid < 2656) { src = Wq; dst = wqb; scale = 1.0f;   base = (bid - 2560) * 2048; }
    else                 { src = Wp; dst = wpb; scale = 1.0f;   base = (bid - 2656) * 2048; }
    const int i = base + threadIdx.x * 8;
    const float4 a = *(const float4*)(src + i);
    const float4 b = *(const float4*)(src + i + 4);
    uint4 o;
    o.x = pk2(scale * a.x, scale * a.y);
    o.y = pk2(scale * a.z, scale * a.w);
    o.z = pk2(scale * b.x, scale * b.y);
    o.w = pk2(scale * b.z, scale * b.w);
    *(uint4*)(dst + i) = o;
}

// ---------------- Kernel 1: QKV projection (X and W pre-converted bf16 -> pure uint4 staging) ----------------
__global__ __launch_bounds__(256) void qkv_gemm(const u16* __restrict__ XB,
                                                const u16* __restrict__ WB,
                                                u16* __restrict__ qo,
                                                u16* __restrict__ ko,
                                                u16* __restrict__ vt) {
    __shared__ u16 SH[2 * 128 * LDK];   // Xs | Ws; reused as transpose buf in v-epilogue
    u16* Xs = SH;
    u16* Ws = SH + 128 * LDK;
    const int t    = threadIdx.x;
    const int m0   = blockIdx.x << 7;
    const int o0   = blockIdx.y << 7;
    const int lane = t & 63;
    const int wid  = t >> 6;
    const int wr   = (wid >> 1) << 6;
    const int wc   = (wid & 1) << 6;
    const int ln   = lane & 15;
    const int quad = lane >> 4;

    const int r  = t >> 1;
    const int hf = (t & 1) << 5;
    const u16* xg = XB + (size_t)(m0 + r) * 256 + hf;
    const u16* wg = WB + (size_t)(o0 + r) * 256 + hf;
    uint4* xls = (uint4*)&Xs[r * LDK + hf];
    uint4* wls = (uint4*)&Ws[r * LDK + hf];

    f32x4 acc[4][4] = {};

    for (int kc = 0; kc < 256; kc += 64) {
        const uint4* xp = (const uint4*)(xg + kc);
        const uint4* wp = (const uint4*)(wg + kc);
        uint4 x0 = xp[0], x1 = xp[1], x2 = xp[2], x3 = xp[3];
        uint4 w0 = wp[0], w1 = wp[1], w2 = wp[2], w3 = wp[3];
        __syncthreads();
        xls[0] = x0; xls[1] = x1; xls[2] = x2; xls[3] = x3;
        wls[0] = w0; wls[1] = w1; wls[2] = w2; wls[3] = w3;
        __syncthreads();
#pragma unroll
        for (int kk = 0; kk < 64; kk += 32) {
            short8 a[4], b[4];
#pragma unroll
            for (int i = 0; i < 4; ++i)
                a[i] = *(const short8*)&Xs[(wr + i * 16 + ln) * LDK + kk + quad * 8];
#pragma unroll
            for (int j = 0; j < 4; ++j)
                b[j] = *(const short8*)&Ws[(wc + j * 16 + ln) * LDK + kk + quad * 8];
#pragma unroll
            for (int i = 0; i < 4; ++i)
#pragma unroll
                for (int j = 0; j < 4; ++j)
                    acc[i][j] = __builtin_amdgcn_mfma_f32_16x16x32_bf16(a[i], b[j], acc[i][j], 0, 0, 0);
        }
    }

    const int which = o0 >> 8;  // 0=q, 1=k, 2=v
    if (which < 2) {
        const float qscale = (which == 0) ? 0.17677669529663689f : 1.0f;  // 32^-0.5 folded into q
        u16* dst = (which == 0) ? qo : ko;
#pragma unroll
        for (int i = 0; i < 4; ++i) {
            const int mb = m0 + wr + i * 16 + quad * 4;  // C/D: row = quad*4 + reg
#pragma unroll
            for (int j = 0; j < 4; ++j) {
                const int o   = o0 + wc + j * 16 + ln;   // C/D: col = lane&15
                const int rem = o & 255;
                const int hh  = rem >> 5;
                const int dd  = rem & 31;
#pragma unroll
                for (int rr = 0; rr < 4; ++rr) {
                    const int m  = mb + rr;
                    const int bt = m >> 9;
                    const int n  = m & 511;
                    dst[(((size_t)bt * 8 + hh) * 512 + n) * 32 + dd] = f2b(acc[i][j][rr] * qscale);
                }
            }
        }
    } else {
        // v: transpose 128m x 128o tile via LDS, packed 16B stores to vt[bh][dd][n]
        __syncthreads();
        u16* T = SH;                           // 128 rows (o_local) x stride 136 (m_local)
#pragma unroll
        for (int i = 0; i < 4; ++i) {
            const int ml = wr + i * 16 + quad * 4;
#pragma unroll
            for (int j = 0; j < 4; ++j) {
                const int ol = wc + j * 16 + ln;
                uint2 pv;
                pv.x = pk2(acc[i][j][0], acc[i][j][1]);
                pv.y = pk2(acc[i][j][2], acc[i][j][3]);
                *(uint2*)&T[ol * 136 + ml] = pv;
            }
        }
        __syncthreads();
        const int row = t >> 1;
        const int seg = (t & 1) << 6;
        const int o   = o0 + row;
        const int rem = o & 255;
        const int hh  = rem >> 5;
        const int dd  = rem & 31;
        const int bt  = m0 >> 9;
        u16* dstv = vt + (((size_t)bt * 8 + hh) * 32 + dd) * 512 + (m0 & 511) + seg;
#pragma unroll
        for (int kk2 = 0; kk2 < 8; ++kk2) {
            uint4 val = *(const uint4*)&T[row * 136 + seg + kk2 * 8];
            *(uint4*)(dstv + kk2 * 8) = val;
        }
    }
}

// ---------------- Kernel 2: MFMA flash attention — per-XCD working-set swizzle ----------------
// NEW swizzle: L&7 = bt>>2  =>  each XCD owns 4 bt (32 bh) x all heads x ALL 4 q-tiles:
// K+VT = 2MB, A = one b x 4 q-tiles = 512KB  =>  2.5MB < 4MB per-XCD L2. K/VT HBM-fetched once.
// (r6..r10 swizzle spread a bh's q-tiles over 4 XCDs -> ~2x HBM refetch + 900cyc staging misses.)
__global__ __launch_bounds__(256, 4) void attn_mfma(const u16* __restrict__ Q,
                                                    const u16* __restrict__ K,
                                                    const u16* __restrict__ VT,
                                                    const u16* __restrict__ AB,
                                                    const int* __restrict__ NF,
                                                    u16* __restrict__ AO) {
    __shared__ u16 Ks[2][64 * 40];    // [buf][key][dim]   80B rows
    __shared__ u16 Vs[2][32 * 72];    // [buf][dim][key]  144B rows (64 keys + 8 pad)
    __shared__ u16 Ps[4][32 * 40];    // per-wave P^T chunk [q][32 keys]
    const int t    = threadIdx.x;
    const int w    = t >> 6;
    const int lane = t & 63;
    const int ln   = lane & 15;
    const int quad = lane >> 4;
    // decode: L&7 -> bt-group (XCD), then (bt_low, h, qt)
    const int L    = blockIdx.x;
    const int rr_  = L >> 3;                 // 0..127
    const int qt   = rr_ & 3;
    const int h    = (rr_ >> 2) & 7;
    const int bt   = (L & 7) * 4 + (rr_ >> 5);
    const int bh   = bt * 8 + h;
    const int q0   = qt * 128 + w * 32;
    const size_t base = (size_t)bh * (512 * 32);
    const int b    = bt / NF[0];
    const u16* Ab  = AB + (size_t)b * 512 * 512;
    const u16* Ar0 = Ab + (size_t)(q0 + ln) * 512 + quad * 4;
    const u16* Ar1 = Ab + (size_t)(q0 + 16 + ln) * 512 + quad * 4;

    // cooperative staging map (2048 bf16 per tile, 256 threads, 1x uint4 each)
    const int krow = t >> 2, kcol = (t & 3) * 8;   // K: 64 rows x 32 dims
    const int vd   = t >> 3, vn   = (t & 7) * 8;   // VT: 32 dims x 64 keys
    const u16* Kg = K + base;
    const u16* Vg = VT + base;

    // ---- prologue: stage jt=0 + preload A regs for jt=0 ----
    {
        uint4 s0 = *(const uint4*)(Kg + (size_t)krow * 32 + kcol);
        uint4 s2 = *(const uint4*)(Vg + (size_t)vd * 512 + vn);
        *(uint4*)&Ks[0][krow * 40 + kcol] = s0;
        *(uint4*)&Vs[0][vd * 72 + vn]     = s2;
    }
    uint2 ar[8];
#pragma unroll
    for (int mt = 0; mt < 4; ++mt) {
        ar[2*mt]     = *(const uint2*)(Ar0 + mt * 16);
        ar[2*mt + 1] = *(const uint2*)(Ar1 + mt * 16);
    }

    short8 qf[2];
#pragma unroll
    for (int nt = 0; nt < 2; ++nt)
        qf[nt] = *(const short8*)(Q + base + (size_t)(q0 + nt * 16 + ln) * 32 + quad * 8);

    f32x4 o[2][2] = {};            // O[q-tile][dim-tile], C-layout
    float lsum0 = 0.f, lsum1 = 0.f;
    __syncthreads();

    int cur = 0;
    for (int jt = 0; jt < 512; jt += 64) {
        const int nxt = cur ^ 1;
        const int jn  = (jt + 64) & 511;   // wrapped: last iter stages tile 0 (unused, harmless)
        // ---- stage next K/V tile into regs (consumed after compute -> full phase of slack) ----
        uint4 t0 = *(const uint4*)(Kg + (size_t)(jn + krow) * 32 + kcol);
        uint4 t2 = *(const uint4*)(Vg + (size_t)vd * 512 + jn + vn);
        // ---- prefetch NEXT jt's A C-operands (used after the barrier -> cannot be sunk) ----
        uint2 arn[8];
#pragma unroll
        for (int mt = 0; mt < 4; ++mt) {
            arn[2*mt]     = *(const uint2*)(Ar0 + jn + mt * 16);
            arn[2*mt + 1] = *(const uint2*)(Ar1 + jn + mt * 16);
        }

        float ps0 = 0.f, ps1 = 0.f;
#pragma unroll
        for (int ks = 0; ks < 2; ++ks) {
            // ---- S chunk: keys ks*32 .. +31 (mt = 2ks, 2ks+1) ----
#pragma unroll
            for (int mm = 0; mm < 2; ++mm) {
                const int mt = 2 * ks + mm;
                short8 ka = *(const short8*)&Ks[cur][(mt * 16 + ln) * 40 + quad * 8];
                f32x4 c0, c1;
                c0[0] = __uint_as_float(ar[2*mt].x << 16);   c0[1] = __uint_as_float(ar[2*mt].x & 0xffff0000u);
                c0[2] = __uint_as_float(ar[2*mt].y << 16);   c0[3] = __uint_as_float(ar[2*mt].y & 0xffff0000u);
                c1[0] = __uint_as_float(ar[2*mt+1].x << 16); c1[1] = __uint_as_float(ar[2*mt+1].x & 0xffff0000u);
                c1[2] = __uint_as_float(ar[2*mt+1].y << 16); c1[3] = __uint_as_float(ar[2*mt+1].y & 0xffff0000u);
                const f32x4 s0 = __builtin_amdgcn_mfma_f32_16x16x32_bf16(ka, qf[0], c0, 0, 0, 0);
                const f32x4 s1 = __builtin_amdgcn_mfma_f32_16x16x32_bf16(ka, qf[1], c1, 0, 0, 0);
                const float p00 = __expf(s0[0]), p01 = __expf(s0[1]), p02 = __expf(s0[2]), p03 = __expf(s0[3]);
                const float p10 = __expf(s1[0]), p11 = __expf(s1[1]), p12 = __expf(s1[2]), p13 = __expf(s1[3]);
                ps0 += (p00 + p01) + (p02 + p03);
                ps1 += (p10 + p11) + (p12 + p13);
                uint2 w0; w0.x = pk2(p00, p01); w0.y = pk2(p02, p03);
                uint2 w1; w1.x = pk2(p10, p11); w1.y = pk2(p12, p13);
                *(uint2*)&Ps[w][ln * 40 + mm * 16 + quad * 4]        = w0;
                *(uint2*)&Ps[w][(16 + ln) * 40 + mm * 16 + quad * 4] = w1;
            }
            // ---- PV chunk (within-wave LDS dependency only) ----
            short8 pa0 = *(const short8*)&Ps[w][ln * 40 + quad * 8];
            short8 pa1 = *(const short8*)&Ps[w][(16 + ln) * 40 + quad * 8];
            short8 vb0 = *(const short8*)&Vs[cur][ln * 72 + ks * 32 + quad * 8];
            short8 vb1 = *(const short8*)&Vs[cur][(16 + ln) * 72 + ks * 32 + quad * 8];
            o[0][0] = __builtin_amdgcn_mfma_f32_16x16x32_bf16(pa0, vb0, o[0][0], 0, 0, 0);
            o[0][1] = __builtin_amdgcn_mfma_f32_16x16x32_bf16(pa0, vb1, o[0][1], 0, 0, 0);
            o[1][0] = __builtin_amdgcn_mfma_f32_16x16x32_bf16(pa1, vb0, o[1][0], 0, 0, 0);
            o[1][1] = __builtin_amdgcn_mfma_f32_16x16x32_bf16(pa1, vb1, o[1][1], 0, 0, 0);
        }

        // ---- write staged regs -> next buffer, single barrier per jt ----
        *(uint4*)&Ks[nxt][krow * 40 + kcol] = t0;
        *(uint4*)&Vs[nxt][vd * 72 + vn]     = t2;
        ps0 += __shfl_xor(ps0, 16); ps0 += __shfl_xor(ps0, 32); lsum0 += ps0;
        ps1 += __shfl_xor(ps1, 16); ps1 += __shfl_xor(ps1, 32); lsum1 += ps1;
        __syncthreads();
#pragma unroll
        for (int i = 0; i < 8; ++i) ar[i] = arn[i];
        cur = nxt;
    }

    // ---- epilogue: O /= l, heads back to [BT,N,D] bf16 ----
#pragma unroll
    for (int r = 0; r < 4; ++r) {
        const int src = quad * 4 + r;
        const float i0 = 1.f / __shfl(lsum0, src);
        const float i1 = 1.f / __shfl(lsum1, src);
        const int n0 = qt * 128 + w * 32 + quad * 4 + r;
#pragma unroll
        for (int ntd = 0; ntd < 2; ++ntd) {
            AO[((size_t)bt * 512 + n0) * 256 + h * 32 + ntd * 16 + ln]      = f2b(o[0][ntd][r] * i0);
            AO[((size_t)bt * 512 + n0 + 16) * 256 + h * 32 + ntd * 16 + ln] = f2b(o[1][ntd][r] * i1);
        }
    }
}

// ---------------- Kernel 3: output projection + bias (W pre-converted bf16) ----------------
__global__ __launch_bounds__(256) void proj_gemm(const u16* __restrict__ X,
                                                 const u16* __restrict__ WB,
                                                 const float* __restrict__ BIAS,
                                                 float* __restrict__ OUT) {
    __shared__ u16 Xs[128 * LDK];
    __shared__ u16 Ws[128 * LDK];
    const int t    = threadIdx.x;
    const int m0   = blockIdx.x << 7;
    const int o0   = blockIdx.y << 7;
    const int lane = t & 63;
    const int wid  = t >> 6;
    const int wr   = (wid >> 1) << 6;
    const int wc   = (wid & 1) << 6;
    const int ln   = lane & 15;
    const int quad = lane >> 4;

    const int r  = t >> 1;
    const int hf = (t & 1) << 5;
    const u16* xg = X + (size_t)(m0 + r) * 256 + hf;
    const u16* wg = WB + (size_t)(o0 + r) * 256 + hf;
    uint4* xls = (uint4*)&Xs[r * LDK + hf];
    uint4* wls = (uint4*)&Ws[r * LDK + hf];

    f32x4 acc[4][4] = {};

    for (int kc = 0; kc < 256; kc += 64) {
        const uint4* xp = (const uint4*)(xg + kc);
        const uint4* wp = (const uint4*)(wg + kc);
        uint4 x0 = xp[0], x1 = xp[1], x2 = xp[2], x3 = xp[3];
        uint4 w0 = wp[0], w1 = wp[1], w2 = wp[2], w3 = wp[3];
        __syncthreads();
        xls[0] = x0; xls[1] = x1; xls[2] = x2; xls[3] = x3;
        wls[0] = w0; wls[1] = w1; wls[2] = w2; wls[3] = w3;
        __syncthreads();
#pragma unroll
        for (int kk = 0; kk < 64; kk += 32) {
            short8 a[4], b[4];
#pragma unroll
            for (int i = 0; i < 4; ++i)
                a[i] = *(const short8*)&Xs[(wr + i * 16 + ln) * LDK + kk + quad * 8];
#pragma unroll
            for (int j = 0; j < 4; ++j)
                b[j] = *(const short8*)&Ws[(wc + j * 16 + ln) * LDK + kk + quad * 8];
#pragma unroll
            for (int i = 0; i < 4; ++i)
#pragma unroll
                for (int j = 0; j < 4; ++j)
                    acc[i][j] = __builtin_amdgcn_mfma_f32_16x16x32_bf16(a[i], b[j], acc[i][j], 0, 0, 0);
        }
    }

#pragma unroll
    for (int i = 0; i < 4; ++i) {
        const int mb = m0 + wr + i * 16 + quad * 4;
#pragma unroll
        for (int j = 0; j < 4; ++j) {
            const int o  = o0 + wc + j * 16 + ln;
            const float bo = BIAS[o];
#pragma unroll
            for (int rr = 0; rr < 4; ++rr) {
                const int m = mb + rr;
                OUT[(size_t)m * 256 + o] = acc[i][j][rr] + bo;
            }
        }
    }
}

extern "C" void kernel_launch(void* const* d_in, const int* in_sizes, int n_in,
                              void* d_out, int out_size, void* d_ws, size_t ws_size,
                              hipStream_t stream) {
    (void)in_sizes; (void)n_in; (void)out_size; (void)ws_size;
    const float* x     = (const float*)d_in[0];   // [32,512,256] fp32
    const float* A     = (const float*)d_in[1];   // [4,512,512]  fp32
    const float* Wqkv  = (const float*)d_in[2];   // [768,256]    fp32
    const float* Wproj = (const float*)d_in[3];   // [256,256]    fp32
    const float* bproj = (const float*)d_in[4];   // [256]        fp32
    const float* lam   = (const float*)d_in[5];   // [1]          fp32
    const int*   nf    = (const int*)d_in[6];     // [1]          int32
    float* out = (float*)d_out;                   // [32,512,256] fp32

    // ws (u16 units): q,k,vt,ao (4,194,304 each) + xb (4,194,304) + AB (1,048,576)
    //                + wqb (196,608) + wpb (65,536)  ≈ 44 MB
    u16* q   = (u16*)d_ws;
    u16* k   = q + 4194304;
    u16* vt  = k + 4194304;
    u16* ao  = vt + 4194304;
    u16* xb  = ao + 4194304;
    u16* AB  = xb + 4194304;
    u16* wqb = AB + 1048576;
    u16* wpb = wqb + 196608;

    prep     <<<dim3(2688), 256, 0, stream>>>(x, A, lam, Wqkv, Wproj, xb, AB, wqb, wpb);
    qkv_gemm <<<dim3(128, 6), 256, 0, stream>>>(xb, wqb, q, k, vt);
    attn_mfma<<<dim3(1024), 256, 0, stream>>>(q, k, vt, AB, nf, ao);
    proj_gemm<<<dim3(128, 2), 256, 0, stream>>>(ao, wpb, bproj, out);
}